// Round 8
// baseline (32776.117 us; speedup 1.0000x reference)
//
#include <hip/hip_runtime.h>
#include <stdint.h>

// PreEncodedGCN on MI355X — round 8.
// vs r7 (single variable): gemm_ms gains a depth-2 register-prefetch software
// pipeline — global loads for iteration k+2 are issued right after the LDS
// stores of iteration k (ping-pong reg buffers), so staging loads stay in
// flight across two full iterations instead of being drained by vmcnt(0)
// every iteration. Everything else unchanged.

typedef unsigned short u16;
typedef __attribute__((ext_vector_type(4))) float f32x4;
typedef __attribute__((ext_vector_type(8))) short short8;

__device__ __forceinline__ float b2f(u16 u){
  union { uint32_t i; float f; } v; v.i = ((uint32_t)u) << 16; return v.f;
}
__device__ __forceinline__ u16 f2b(float f){
  union { float f; uint32_t i; } v; v.f = f;
  uint32_t u = v.i;
  return (u16)((u + 0x7FFFu + ((u >> 16) & 1u)) >> 16);
}
__device__ __forceinline__ u16 rdw(const void* p, size_t i, int f32){
  return f32 ? f2b(((const float*)p)[i]) : ((const u16*)p)[i];
}

// ---------------- dtype detector: 1 = fp32, 0 = bf16 ------------------------
__global__ void detect_dtype(const u16* enc16, int* flag){
  __shared__ int cnt;
  if (threadIdx.x == 0) cnt = 0;
  __syncthreads();
  unsigned u = enc16[threadIdx.x * 2];
  int e = (u >> 7) & 0xFF;
  if (e >= 100 && e <= 140) atomicAdd(&cnt, 1);
  __syncthreads();
  if (threadIdx.x == 0) flag[0] = (cnt < 128) ? 1 : 0;
}

// ---------------- batched small-weight conversion ---------------------------
// arena u16 offsets: spk@0(1024) c1@1024(128) c3@1152(128) b1@1280 b2@1536
// b3@1792 b4@2048(256ea) bd1@2304(128) bd2@10624(64) wd3@10688(64)
// bd3@10752(1) wd2T@10880(8192, [o*128+k])
__global__ void cvt_small(const void* spk, const void* c1, const void* c3,
                          const void* b1, const void* b2, const void* b3,
                          const void* b4, const void* bd1, const void* wd2,
                          const void* bd2, const void* wd3, const void* bd3,
                          u16* __restrict__ arena, const int* __restrict__ flag)
{
  int f = *flag;
  int i = blockIdx.x * blockDim.x + threadIdx.x;
  if (i < 1024) { arena[i] = rdw(spk, i, f); return; } i -= 1024;
  if (i < 128)  { arena[1024 + i] = rdw(c1, i, f); return; } i -= 128;
  if (i < 128)  { arena[1152 + i] = rdw(c3, i, f); return; } i -= 128;
  if (i < 256)  { arena[1280 + i] = rdw(b1, i, f); return; } i -= 256;
  if (i < 256)  { arena[1536 + i] = rdw(b2, i, f); return; } i -= 256;
  if (i < 256)  { arena[1792 + i] = rdw(b3, i, f); return; } i -= 256;
  if (i < 256)  { arena[2048 + i] = rdw(b4, i, f); return; } i -= 256;
  if (i < 128)  { arena[2304 + i] = rdw(bd1, i, f); return; } i -= 128;
  if (i < 64)   { arena[10624 + i] = rdw(bd2, i, f); return; } i -= 64;
  if (i < 64)   { arena[10688 + i] = rdw(wd3, i, f); return; } i -= 64;
  if (i < 1)    { arena[10752 + i] = rdw(bd3, i, f); return; } i -= 1;
  if (i < 8192) { int o = i >> 7, k = i & 127;          // wd2T[o,k] = wd2[k,o]
    arena[10880 + i] = rdw(wd2, k * 64 + o, f); }
}

// ---------------- vectorized convert (n multiple of 4) ----------------------
__global__ void cvt4(const void* __restrict__ in, u16* __restrict__ out, int n,
                     const int* __restrict__ flag){
  int i = (blockIdx.x * blockDim.x + threadIdx.x) * 4;
  if (i >= n) return;
  ushort4 o;
  if (*flag) {
    float4 v = *(const float4*)((const float*)in + i);
    o.x = f2b(v.x); o.y = f2b(v.y); o.z = f2b(v.z); o.w = f2b(v.w);
  } else {
    o = *(const ushort4*)((const u16*)in + i);
  }
  *(ushort4*)(out + i) = o;
}

// ---------------- weight packing: transpose B matrices to [NOUT, K] ----------
__global__ void pack_weights(const void* __restrict__ bases1, const void* __restrict__ root1,
                             const void* __restrict__ w2_rel, const void* __restrict__ w2_root,
                             const void* __restrict__ bases3, const void* __restrict__ root3,
                             const void* __restrict__ w4_rel, const void* __restrict__ w4_root,
                             const void* __restrict__ wd1,
                             u16* __restrict__ B1t, u16* __restrict__ B3t,
                             u16* __restrict__ B2t, u16* __restrict__ B4t,
                             u16* __restrict__ D1t, const int* __restrict__ flag)
{
  int f = *flag;
  int idx = blockIdx.x * blockDim.x + threadIdx.x;
  if (idx < 256*2304) { int o = idx / 2304, k = idx % 2304;
    B1t[idx] = (k < 2048) ? rdw(bases1, k*256 + o, f) : rdw(root1, (k-2048)*256 + o, f); return; }
  idx -= 256*2304;
  if (idx < 256*2304) { int o = idx / 2304, k = idx % 2304;
    B3t[idx] = (k < 2048) ? rdw(bases3, k*256 + o, f) : rdw(root3, (k-2048)*256 + o, f); return; }
  idx -= 256*2304;
  if (idx < 256*512) { int o = idx / 512, k = idx % 512;
    B2t[idx] = (k < 256) ? rdw(w2_rel, k*256 + o, f) : rdw(w2_root, (k-256)*256 + o, f); return; }
  idx -= 256*512;
  if (idx < 256*512) { int o = idx / 512, k = idx % 512;
    B4t[idx] = (k < 256) ? rdw(w4_rel, k*256 + o, f) : rdw(w4_root, (k-256)*256 + o, f); return; }
  idx -= 256*512;
  if (idx < 128*768) { int o = idx / 768, k = idx % 768;
    D1t[idx] = rdw(wd1, k*128 + o, f); }
}

// ---------------- x = encoding + spk_table[speaker] -------------------------
__global__ void build_x(const void* __restrict__ enc, const int* __restrict__ speaker,
                        const u16* __restrict__ spkA /* bf16 [4,256] */,
                        u16* __restrict__ X /* [N,256] */, int N,
                        const int* __restrict__ flag)
{
  int f = *flag;
  int idx = blockIdx.x * blockDim.x + threadIdx.x;
  if (idx >= N * 64) return;
  int n = idx >> 6, c = (idx & 63) * 4;
  int sp = speaker[n];
  ushort4 sv = *(const ushort4*)(spkA + (size_t)sp*256 + c);
  float e0, e1, e2, e3;
  if (f) {
    float4 ev = *(const float4*)((const float*)enc + (size_t)n*256 + c);
    e0 = ev.x; e1 = ev.y; e2 = ev.z; e3 = ev.w;
  } else {
    ushort4 ev = *(const ushort4*)((const u16*)enc + (size_t)n*256 + c);
    e0 = b2f(ev.x); e1 = b2f(ev.y); e2 = b2f(ev.z); e3 = b2f(ev.w);
  }
  ushort4 xv;
  xv.x = f2b(e0 + b2f(sv.x));
  xv.y = f2b(e1 + b2f(sv.y));
  xv.z = f2b(e2 + b2f(sv.z));
  xv.w = f2b(e3 + b2f(sv.w));
  *(ushort4*)(X + (size_t)n*256 + c) = xv;
}

// ---------------- dst-degree histogram ---------------------------------------
__global__ void edge_hist(const int* __restrict__ ei, int* cnt_dst, int E)
{
  int e = blockIdx.x * blockDim.x + threadIdx.x;
  if (e >= E) return;
  atomicAdd(&cnt_dst[ei[E + e]], 1);
}

// ---------------- 3-phase parallel exclusive scan ---------------------------
__global__ void scan_p1(const int* __restrict__ cnt, int* __restrict__ partial,
                        int* __restrict__ bsum, int N)
{
  __shared__ int s[256];
  int t = threadIdx.x;
  int g = blockIdx.x * 256 + t;
  int v = (g < N) ? cnt[g] : 0;
  s[t] = v; __syncthreads();
  #pragma unroll
  for (int off = 1; off < 256; off <<= 1) {
    int u = (t >= off) ? s[t - off] : 0;
    __syncthreads();
    s[t] += u;
    __syncthreads();
  }
  partial[g] = s[t];                       // inclusive
  if (t == 255) bsum[blockIdx.x] = s[255];
}

__global__ void scan_p2(int* __restrict__ bsum, int nb)
{
  __shared__ int s[1024];
  int t = threadIdx.x;
  int v = (t < nb) ? bsum[t] : 0;
  s[t] = v; __syncthreads();
  #pragma unroll
  for (int off = 1; off < 1024; off <<= 1) {
    int u = (t >= off) ? s[t - off] : 0;
    __syncthreads();
    s[t] += u;
    __syncthreads();
  }
  if (t < nb) bsum[t] = s[t] - v;          // exclusive
  if (t == nb - 1) bsum[nb] = s[t];        // total
}

__global__ void scan_p3(const int* __restrict__ cnt, const int* __restrict__ partial,
                        const int* __restrict__ bsum, int* __restrict__ basep, int N)
{
  int g = blockIdx.x * 256 + threadIdx.x;
  if (g < N) basep[g] = partial[g] - cnt[g] + bsum[blockIdx.x];
  if (g == 0) basep[N] = bsum[(N + 255) / 256];
}

// ---------------- scatter edges into dst-sorted order, packed ---------------
__global__ void edge_scatter(const int* __restrict__ ei, const int* __restrict__ et,
                             const int* __restrict__ est, const int* __restrict__ basep,
                             int* cursor, int* __restrict__ esorted, int E)
{
  int e = blockIdx.x * blockDim.x + threadIdx.x;
  if (e >= E) return;
  int d = ei[E + e];
  int pos = basep[d] + atomicAdd(&cursor[d], 1);
  esorted[pos] = ei[e] | (et[e] << 17) | (est[e] << 21);  // src<2^17, 4+4 bits rels
}

// ------- merged RGCN aggregation (conv1+conv3), in-wave rel counts ----------
__global__ __launch_bounds__(256) void rgcn_agg2(
    const int* __restrict__ esorted, const int* __restrict__ basep,
    const u16* __restrict__ X /* [N,256] */,
    const u16* __restrict__ comp1 /* bf16 [16,8] */,
    const u16* __restrict__ comp3 /* bf16 [16,8] */,
    u16* __restrict__ Mix1 /* [CR,2048] */,
    u16* __restrict__ Mix3 /* [CR,2048] */,
    int n0, int CR)
{
  __shared__ float sc1[128], sc3[128];
  if (threadIdx.x < 128) sc1[threadIdx.x] = b2f(comp1[threadIdx.x]);
  else sc3[threadIdx.x - 128] = b2f(comp3[threadIdx.x - 128]);
  __syncthreads();
  int nl = blockIdx.x * 4 + (threadIdx.x >> 6);
  if (nl >= CR) return;
  int n = n0 + nl;
  int lane = threadIdx.x & 63;
  int e0 = basep[n], e1 = basep[n + 1];
  // counting pass: lanes 0-15 count et==lane, lanes 16-31 count est==lane-16
  int myrel = lane & 15;
  int cnt = 0;
  for (int e = e0; e < e1; e++) {
    int rec = esorted[e];
    int r1 = (rec >> 17) & 15, r3 = (rec >> 21) & 15;
    if (lane < 16) cnt += (r1 == myrel);
    else if (lane < 32) cnt += (r3 == myrel);
  }
  float invv = 1.0f / (float)(cnt > 1 ? cnt : 1);
  // main pass
  float acc1[8][4] = {}, acc3[8][4] = {};
  for (int e = e0; e < e1; e++) {
    int rec = esorted[e];
    int src = rec & 0x1FFFF;
    int r1 = (rec >> 17) & 15, r3 = (rec >> 21) & 15;
    float iv1 = __shfl(invv, r1);
    float iv3 = __shfl(invv, 16 + r3);
    ushort4 xr = *(const ushort4*)(X + (size_t)src * 256 + lane * 4);
    float x0 = b2f(xr.x), x1 = b2f(xr.y), x2 = b2f(xr.z), x3 = b2f(xr.w);
    const float* c1p = sc1 + r1 * 8;
    const float* c3p = sc3 + r3 * 8;
    #pragma unroll
    for (int b = 0; b < 8; b++) {
      float w1 = c1p[b] * iv1;
      acc1[b][0] += w1 * x0; acc1[b][1] += w1 * x1;
      acc1[b][2] += w1 * x2; acc1[b][3] += w1 * x3;
      float w3 = c3p[b] * iv3;
      acc3[b][0] += w3 * x0; acc3[b][1] += w3 * x1;
      acc3[b][2] += w3 * x2; acc3[b][3] += w3 * x3;
    }
  }
  #pragma unroll
  for (int b = 0; b < 8; b++) {
    ushort4 o1, o3;
    o1.x = f2b(acc1[b][0]); o1.y = f2b(acc1[b][1]);
    o1.z = f2b(acc1[b][2]); o1.w = f2b(acc1[b][3]);
    o3.x = f2b(acc3[b][0]); o3.y = f2b(acc3[b][1]);
    o3.z = f2b(acc3[b][2]); o3.w = f2b(acc3[b][3]);
    *(ushort4*)(Mix1 + (size_t)nl * 2048 + b * 256 + lane * 4) = o1;
    *(ushort4*)(Mix3 + (size_t)nl * 2048 + b * 256 + lane * 4) = o3;
  }
}

// -------- GraphConv sum-aggregation: 16B/lane, 2 edges per wave-iter --------
__global__ __launch_bounds__(256) void gconv_agg(
    const int* __restrict__ esorted, const int* __restrict__ basep,
    const u16* __restrict__ Hin /* [N,256] */,
    u16* __restrict__ Agg /* [N,256] */, int N)
{
  int n = blockIdx.x * 4 + (threadIdx.x >> 6);
  if (n >= N) return;
  int lane = threadIdx.x & 63;
  int half = lane >> 5, l32 = lane & 31;
  float a[8] = {};
  int e0 = basep[n], e1 = basep[n + 1];
  for (int e = e0; e < e1; e += 2) {
    int ee = e + half;
    bool ok = ee < e1;
    int src = esorted[ok ? ee : e] & 0x1FFFF;
    short8 hv = *(const short8*)(Hin + (size_t)src * 256 + l32 * 8);
    if (ok) {
      #pragma unroll
      for (int j = 0; j < 8; j++) a[j] += b2f((u16)hv[j]);
    }
  }
  #pragma unroll
  for (int j = 0; j < 8; j++) a[j] += __shfl_xor(a[j], 32);
  if (half == 0) {
    short8 o;
    #pragma unroll
    for (int j = 0; j < 8; j++) o[j] = (short)f2b(a[j]);
    *(short8*)(Agg + (size_t)n * 256 + l32 * 8) = o;
  }
}

// ------------- multi-source bf16 MFMA GEMM, 128x32 tiles, reg-prefetch ------
// C = [A0|A1|A2] @ Bt^T + bias. Depth-2 register pipeline: loads for k0+2BK
// issued right after the LDS stores of k0 — staging loads stay in flight
// across two iterations (vmcnt(5) waits, never a full drain).
__global__ __launch_bounds__(256) void gemm_ms(
    const u16* __restrict__ A0, int lda0,
    const u16* __restrict__ A1, int lda1,
    const u16* __restrict__ A2, int lda2,
    int c1, int c2,
    const u16* __restrict__ Bt, /* [nout, K] */
    const u16* __restrict__ bias,
    u16* __restrict__ Cout, int ldc,
    int M, int K, int relu, int nout, int nx,
    const u16* __restrict__ A0d, const u16* __restrict__ Btd,
    const u16* __restrict__ biasd, u16* __restrict__ Coutd)
{
  constexpr int BK = 64;
  constexpr int LDR = 72;                 // padded row stride (u16)
  __shared__ u16 As[128 * LDR];
  __shared__ u16 Bs[32 * LDR];
  int bi = blockIdx.x;
  const u16* A0u = A0; const u16* Btu = Bt; const u16* biasu = bias;
  u16* Cu = Cout;
  if (bi >= nx) { bi -= nx; A0u = A0d; Btu = Btd; biasu = biasd; Cu = Coutd; }
  int nblk = nout >> 5;
  int grpw = nblk << 3;                   // 8*nblk
  int g = bi / grpw, r = bi % grpw;
  int gm = g * 8 + (r & 7);
  int bm = gm * 128;
  if (bm >= M) return;                    // uniform per block — safe
  int bn = (r >> 3) * 32;

  int tid = threadIdx.x;
  int lane = tid & 63;
  int wid = tid >> 6;
  f32x4 acc[2][2];
  #pragma unroll
  for (int i = 0; i < 2; i++)
    #pragma unroll
    for (int j = 0; j < 2; j++) acc[i][j] = (f32x4)0.0f;

  int sr = tid >> 3;            // 0..31 staging row within group
  int sc = (tid & 7) * 8;       // 0..56 staging col (u16)
  int lm = lane & 15, quad = lane >> 4;

  short8 va[2][4], vb[2];
  auto issue = [&](int s, int k0) {
    const u16* srcp; int ldas, kO;       // wave-uniform (k0 uniform)
    if (k0 < c1)      { srcp = A0u; ldas = lda0; kO = k0; }
    else if (k0 < c2) { srcp = A1;  ldas = lda1; kO = k0 - c1; }
    else              { srcp = A2;  ldas = lda2; kO = k0 - c2; }
    #pragma unroll
    for (int gg = 0; gg < 4; gg++) {
      int gr = bm + gg * 32 + sr; gr = gr < M ? gr : M - 1;
      va[s][gg] = *(const short8*)(srcp + (size_t)gr * ldas + kO + sc);
    }
    int br = bn + sr; br = br < nout ? br : nout - 1;
    vb[s] = *(const short8*)(Btu + (size_t)br * K + k0 + sc);
  };

  issue(0, 0);
  if (BK < K) issue(1, BK);
  int s = 0;
  for (int k0 = 0; k0 < K; k0 += BK, s ^= 1) {
    #pragma unroll
    for (int gg = 0; gg < 4; gg++)
      *(short8*)(As + (gg * 32 + sr) * LDR + sc) = va[s][gg];
    *(short8*)(Bs + sr * LDR + sc) = vb[s];
    if (k0 + 2 * BK < K) issue(s, k0 + 2 * BK);   // in flight over 2 iters
    __syncthreads();
    #pragma unroll
    for (int kk = 0; kk < BK; kk += 32) {
      short8 af[2], bfv[2];
      #pragma unroll
      for (int mi = 0; mi < 2; mi++) {
        int m = wid * 32 + mi * 16 + lm;
        af[mi] = *(const short8*)(As + m * LDR + kk + quad * 8);
      }
      #pragma unroll
      for (int ni = 0; ni < 2; ni++) {
        int nn = ni * 16 + lm;
        bfv[ni] = *(const short8*)(Bs + nn * LDR + kk + quad * 8);
      }
      #pragma unroll
      for (int mi = 0; mi < 2; mi++)
        #pragma unroll
        for (int ni = 0; ni < 2; ni++)
          acc[mi][ni] = __builtin_amdgcn_mfma_f32_16x16x32_bf16(
              af[mi], bfv[ni], acc[mi][ni], 0, 0, 0);
    }
    __syncthreads();
  }
  #pragma unroll
  for (int ni = 0; ni < 2; ni++) {
    int gn = bn + ni * 16 + lm;
    float bv = b2f(biasu[gn]);
    #pragma unroll
    for (int mi = 0; mi < 2; mi++) {
      int rbase = bm + wid * 32 + mi * 16 + quad * 4;
      #pragma unroll
      for (int rr = 0; rr < 4; rr++) {
        int gmr = rbase + rr;
        if (gmr < M) {
          float v = acc[mi][ni][rr] + bv;
          if (relu) v = fmaxf(v, 0.f);
          Cu[(size_t)gmr * ldc + gn] = f2b(v);
        }
      }
    }
  }
}

// ---------------- final dot: out[n] = sum_o h2m[n,o]*wd3[o] + bd3 -----------
__global__ __launch_bounds__(256) void mlp_tail2(
    const u16* __restrict__ h2m, const u16* __restrict__ wd3,
    const u16* __restrict__ bd3, void* __restrict__ outp, int N,
    const int* __restrict__ flag)
{
  int n = blockIdx.x * 4 + (threadIdx.x >> 6);
  if (n >= N) return;
  int lane = threadIdx.x & 63;
  float r = b2f(h2m[(size_t)n * 64 + lane]) * b2f(wd3[lane]);
  #pragma unroll
  for (int off = 32; off > 0; off >>= 1) r += __shfl_xor(r, off, 64);
  if (lane == 0) {
    float v = r + b2f(bd3[0]);
    if (*flag) ((float*)outp)[n] = v;
    else       ((u16*)outp)[n] = f2b(v);
  }
}

__global__ void sentinel(u16* out, int n, float code){
  int i = blockIdx.x * blockDim.x + threadIdx.x;
  if (i < n) out[i] = f2b(code);
}

extern "C" void kernel_launch(void* const* d_in, const int* in_sizes, int n_in,
                              void* d_out, int out_size, void* d_ws, size_t ws_size,
                              hipStream_t stream)
{
  const void* enc     = d_in[0];
  const int* speaker  = (const int*)d_in[1];
  const int* ei       = (const int*)d_in[2];
  const int* et       = (const int*)d_in[3];
  const int* est      = (const int*)d_in[4];
  const void* spk_tab = d_in[5];
  const void* comp1   = d_in[6];
  const void* bases1  = d_in[7];
  const void* root1   = d_in[8];
  const void* b1      = d_in[9];
  const void* w2_rel  = d_in[10];
  const void* b2      = d_in[11];
  const void* w2_root = d_in[12];
  const void* comp3   = d_in[13];
  const void* bases3  = d_in[14];
  const void* root3   = d_in[15];
  const void* b3      = d_in[16];
  const void* w4_rel  = d_in[17];
  const void* b4      = d_in[18];
  const void* w4_root = d_in[19];
  const void* wd1     = d_in[20];
  const void* bd1     = d_in[21];
  const void* wd2     = d_in[22];
  const void* bd2     = d_in[23];
  const void* wd3     = d_in[24];
  const void* bd3     = d_in[25];

  int N = in_sizes[1];     // 60000
  int E = in_sizes[3];     // 480000
  int nb = (N + 255) / 256;

  char* ws = (char*)d_ws;
  size_t off = 0;
  auto alloc = [&](size_t bytes) -> char* {
    char* p = ws + off; off = (off + bytes + 255) & ~(size_t)255; return p;
  };
  u16* X    = (u16*)alloc((size_t)N * 256 * 2);   // x = enc+spk; later bf16 enc
  u16* hA   = (u16*)alloc((size_t)N * 256 * 2);   // conv1 rgcn out
  u16* hA3  = (u16*)alloc((size_t)N * 256 * 2);   // conv3 rgcn out
  u16* hB   = (u16*)alloc((size_t)N * 256 * 2);   // h1 final
  u16* hC   = (u16*)alloc((size_t)N * 256 * 2);   // h2 final
  u16* AggB = (u16*)alloc((size_t)N * 256 * 2);   // gconv agg; aliased below
  u16* h1m  = AggB;                                // [N,128] after AggB dead
  u16* h2m  = AggB + (size_t)N * 128;              // [N,64]
  u16* B1t  = (u16*)alloc((size_t)256 * 2304 * 2);
  u16* B3t  = (u16*)alloc((size_t)256 * 2304 * 2);
  u16* B2t  = (u16*)alloc((size_t)256 * 512 * 2);
  u16* B4t  = (u16*)alloc((size_t)256 * 512 * 2);
  u16* D1t  = (u16*)alloc((size_t)128 * 768 * 2);
  u16* arena = (u16*)alloc((size_t)20480 * 2);
  int* flag    = (int*)alloc(256);
  // contiguous zero-init region: cnt_dst, cursor
  int* cnt_dst = (int*)alloc((size_t)N * 4);
  int* cursor  = (int*)alloc((size_t)N * 4);
  size_t zspan = (size_t)((char*)cursor - (char*)cnt_dst) + (size_t)N * 4;
  int* basep   = (int*)alloc((size_t)(N + 1) * 4);
  int* partial = (int*)alloc((size_t)nb * 256 * 4);
  int* bsum    = (int*)alloc((size_t)2048 * 4);
  int* esorted = (int*)alloc((size_t)E * 4);

  // arena layout (u16 offsets)
  u16* spkA   = arena + 0;
  u16* comp1A = arena + 1024;
  u16* comp3A = arena + 1152;
  u16* b1A    = arena + 1280;
  u16* b2A    = arena + 1536;
  u16* b3A    = arena + 1792;
  u16* b4A    = arena + 2048;
  u16* bd1A   = arena + 2304;
  u16* bd2A   = arena + 10624;
  u16* wd3A   = arena + 10688;
  u16* bd3A   = arena + 10752;
  u16* wd2T   = arena + 10880;   // [64,128]

  // Mix1+Mix3 chunk: 8 KB per row
  size_t rem = (ws_size > off) ? (ws_size - off) : 0;
  long crl = (long)(rem / (4096 * 2));
  int chunk_rows = (int)((crl / 128) * 128);
  int Mpad = ((N + 127) / 128) * 128;
  if (chunk_rows > Mpad) chunk_rows = Mpad;

  if (chunk_rows < 128) {
    float code = 2000.0f + (float)(ws_size >> 20);
    sentinel<<<(out_size + 255) / 256, 256, 0, stream>>>((u16*)d_out, out_size, code);
    return;
  }
  u16* Mix1blk = (u16*)(ws + off);
  u16* Mix3blk = Mix1blk + (size_t)chunk_rows * 2048;

  hipMemsetAsync(cnt_dst, 0, zspan, stream);

  detect_dtype<<<1, 256, 0, stream>>>((const u16*)enc, flag);
  cvt_small<<<75, 256, 0, stream>>>(spk_tab, comp1, comp3, b1, b2, b3, b4,
                                    bd1, wd2, bd2, wd3, bd3, arena, flag);

  int totpack = 256*2304*2 + 256*512*2 + 128*768;
  pack_weights<<<(totpack + 255) / 256, 256, 0, stream>>>(
      bases1, root1, w2_rel, w2_root, bases3, root3, w4_rel, w4_root, wd1,
      B1t, B3t, B2t, B4t, D1t, flag);
  build_x<<<(N * 64 + 255) / 256, 256, 0, stream>>>(enc, speaker, spkA, X, N, flag);
  edge_hist<<<(E + 255) / 256, 256, 0, stream>>>(ei, cnt_dst, E);
  scan_p1<<<nb, 256, 0, stream>>>(cnt_dst, partial, bsum, N);
  scan_p2<<<1, 1024, 0, stream>>>(bsum, nb);
  scan_p3<<<nb, 256, 0, stream>>>(cnt_dst, partial, bsum, basep, N);
  edge_scatter<<<(E + 255) / 256, 256, 0, stream>>>(ei, et, est, basep, cursor, esorted, E);

  int nb4 = (N + 3) / 4;
  const u16* nul = (const u16*)nullptr;
  auto nx_for = [](int M_, int nout_) {
    int mg = (M_ + 127) / 128;
    int grpw = (nout_ / 32) * 8;
    return ((mg + 7) / 8) * grpw;
  };

  // convs: merged aggregation + dual GEMM per chunk
  for (int n0 = 0; n0 < N; n0 += chunk_rows) {
    int CR = (N - n0 < chunk_rows) ? (N - n0) : chunk_rows;
    rgcn_agg2<<<(CR + 3) / 4, 256, 0, stream>>>(esorted, basep, X, comp1A, comp3A,
                                                Mix1blk, Mix3blk, n0, CR);
    int nx = nx_for(CR, 256);
    gemm_ms<<<2 * nx, 256, 0, stream>>>(
        Mix1blk, 2048, X + (size_t)n0 * 256, 256, nul, 0, 2048, 2304,
        B1t, b1A, hA + (size_t)n0 * 256, 256, CR, 2304, 0, 256, nx,
        Mix3blk, B3t, b3A, hA3 + (size_t)n0 * 256);
  }
  // gconv2: agg(h1_rgcn) -> [agg|h] @ [w2_rel;w2_root] -> hB
  int nxN = nx_for(N, 256);
  gconv_agg<<<nb4, 256, 0, stream>>>(esorted, basep, hA, AggB, N);
  gemm_ms<<<nxN, 256, 0, stream>>>(
      AggB, 256, hA, 256, nul, 0, 256, 512,
      B2t, b2A, hB, 256, N, 512, 0, 256, nxN, nul, nul, nul, (u16*)nullptr);
  // gconv4
  gconv_agg<<<nb4, 256, 0, stream>>>(esorted, basep, hA3, AggB, N);
  cvt4<<<(N * 64 + 255) / 256, 256, 0, stream>>>(enc, X, N * 256, flag);  // X dead -> bf16 enc
  gemm_ms<<<nxN, 256, 0, stream>>>(
      AggB, 256, hA3, 256, nul, 0, 256, 512,
      B4t, b4A, hC, 256, N, 512, 0, 256, nxN, nul, nul, nul, (u16*)nullptr);

  // MLP layer 1: [enc|h1|h2] @ wd1 (+bd1, relu) -> h1m [N,128]
  int nx1 = nx_for(N, 128);
  gemm_ms<<<nx1, 256, 0, stream>>>(
      X, 256, hB, 256, hC, 256, 256, 512,
      D1t, bd1A, h1m, 128, N, 768, 1, 128, nx1, nul, nul, nul, (u16*)nullptr);
  // MLP layer 2: h1m @ wd2 (+bd2, relu) -> h2m [N,64]
  int nx2 = nx_for(N, 64);
  gemm_ms<<<nx2, 256, 0, stream>>>(
      h1m, 128, nul, 0, nul, 0, 128, 128,
      wd2T, bd2A, h2m, 64, N, 128, 1, 64, nx2, nul, nul, nul, (u16*)nullptr);
  // MLP layer 3
  mlp_tail2<<<nb4, 256, 0, stream>>>(h2m, wd3A, bd3A, d_out, N, flag);
}

// Round 9
// 1002.289 us; speedup vs baseline: 32.7013x; 32.7013x over previous
//
#include <hip/hip_runtime.h>
#include <stdint.h>

// PreEncodedGCN on MI355X — round 9.
// r8's depth-2 prefetch re-landed WITHOUT dynamic buffer indexing (r8 put the
// ping-pong regs in scratch -> 68x regression). Two named register buffer
// sets + K-loop unrolled x2 (all K are multiples of 128), so promotion to
// VGPRs is guaranteed. Everything else identical to r7/r8.

typedef unsigned short u16;
typedef __attribute__((ext_vector_type(4))) float f32x4;
typedef __attribute__((ext_vector_type(8))) short short8;

__device__ __forceinline__ float b2f(u16 u){
  union { uint32_t i; float f; } v; v.i = ((uint32_t)u) << 16; return v.f;
}
__device__ __forceinline__ u16 f2b(float f){
  union { float f; uint32_t i; } v; v.f = f;
  uint32_t u = v.i;
  return (u16)((u + 0x7FFFu + ((u >> 16) & 1u)) >> 16);
}
__device__ __forceinline__ u16 rdw(const void* p, size_t i, int f32){
  return f32 ? f2b(((const float*)p)[i]) : ((const u16*)p)[i];
}

// ---------------- dtype detector: 1 = fp32, 0 = bf16 ------------------------
__global__ void detect_dtype(const u16* enc16, int* flag){
  __shared__ int cnt;
  if (threadIdx.x == 0) cnt = 0;
  __syncthreads();
  unsigned u = enc16[threadIdx.x * 2];
  int e = (u >> 7) & 0xFF;
  if (e >= 100 && e <= 140) atomicAdd(&cnt, 1);
  __syncthreads();
  if (threadIdx.x == 0) flag[0] = (cnt < 128) ? 1 : 0;
}

// ---------------- batched small-weight conversion ---------------------------
// arena u16 offsets: spk@0(1024) c1@1024(128) c3@1152(128) b1@1280 b2@1536
// b3@1792 b4@2048(256ea) bd1@2304(128) bd2@10624(64) wd3@10688(64)
// bd3@10752(1) wd2T@10880(8192, [o*128+k])
__global__ void cvt_small(const void* spk, const void* c1, const void* c3,
                          const void* b1, const void* b2, const void* b3,
                          const void* b4, const void* bd1, const void* wd2,
                          const void* bd2, const void* wd3, const void* bd3,
                          u16* __restrict__ arena, const int* __restrict__ flag)
{
  int f = *flag;
  int i = blockIdx.x * blockDim.x + threadIdx.x;
  if (i < 1024) { arena[i] = rdw(spk, i, f); return; } i -= 1024;
  if (i < 128)  { arena[1024 + i] = rdw(c1, i, f); return; } i -= 128;
  if (i < 128)  { arena[1152 + i] = rdw(c3, i, f); return; } i -= 128;
  if (i < 256)  { arena[1280 + i] = rdw(b1, i, f); return; } i -= 256;
  if (i < 256)  { arena[1536 + i] = rdw(b2, i, f); return; } i -= 256;
  if (i < 256)  { arena[1792 + i] = rdw(b3, i, f); return; } i -= 256;
  if (i < 256)  { arena[2048 + i] = rdw(b4, i, f); return; } i -= 256;
  if (i < 128)  { arena[2304 + i] = rdw(bd1, i, f); return; } i -= 128;
  if (i < 64)   { arena[10624 + i] = rdw(bd2, i, f); return; } i -= 64;
  if (i < 64)   { arena[10688 + i] = rdw(wd3, i, f); return; } i -= 64;
  if (i < 1)    { arena[10752 + i] = rdw(bd3, i, f); return; } i -= 1;
  if (i < 8192) { int o = i >> 7, k = i & 127;          // wd2T[o,k] = wd2[k,o]
    arena[10880 + i] = rdw(wd2, k * 64 + o, f); }
}

// ---------------- vectorized convert (n multiple of 4) ----------------------
__global__ void cvt4(const void* __restrict__ in, u16* __restrict__ out, int n,
                     const int* __restrict__ flag){
  int i = (blockIdx.x * blockDim.x + threadIdx.x) * 4;
  if (i >= n) return;
  ushort4 o;
  if (*flag) {
    float4 v = *(const float4*)((const float*)in + i);
    o.x = f2b(v.x); o.y = f2b(v.y); o.z = f2b(v.z); o.w = f2b(v.w);
  } else {
    o = *(const ushort4*)((const u16*)in + i);
  }
  *(ushort4*)(out + i) = o;
}

// ---------------- weight packing: transpose B matrices to [NOUT, K] ----------
__global__ void pack_weights(const void* __restrict__ bases1, const void* __restrict__ root1,
                             const void* __restrict__ w2_rel, const void* __restrict__ w2_root,
                             const void* __restrict__ bases3, const void* __restrict__ root3,
                             const void* __restrict__ w4_rel, const void* __restrict__ w4_root,
                             const void* __restrict__ wd1,
                             u16* __restrict__ B1t, u16* __restrict__ B3t,
                             u16* __restrict__ B2t, u16* __restrict__ B4t,
                             u16* __restrict__ D1t, const int* __restrict__ flag)
{
  int f = *flag;
  int idx = blockIdx.x * blockDim.x + threadIdx.x;
  if (idx < 256*2304) { int o = idx / 2304, k = idx % 2304;
    B1t[idx] = (k < 2048) ? rdw(bases1, k*256 + o, f) : rdw(root1, (k-2048)*256 + o, f); return; }
  idx -= 256*2304;
  if (idx < 256*2304) { int o = idx / 2304, k = idx % 2304;
    B3t[idx] = (k < 2048) ? rdw(bases3, k*256 + o, f) : rdw(root3, (k-2048)*256 + o, f); return; }
  idx -= 256*2304;
  if (idx < 256*512) { int o = idx / 512, k = idx % 512;
    B2t[idx] = (k < 256) ? rdw(w2_rel, k*256 + o, f) : rdw(w2_root, (k-256)*256 + o, f); return; }
  idx -= 256*512;
  if (idx < 256*512) { int o = idx / 512, k = idx % 512;
    B4t[idx] = (k < 256) ? rdw(w4_rel, k*256 + o, f) : rdw(w4_root, (k-256)*256 + o, f); return; }
  idx -= 256*512;
  if (idx < 128*768) { int o = idx / 768, k = idx % 768;
    D1t[idx] = rdw(wd1, k*128 + o, f); }
}

// ---------------- x = encoding + spk_table[speaker] -------------------------
__global__ void build_x(const void* __restrict__ enc, const int* __restrict__ speaker,
                        const u16* __restrict__ spkA /* bf16 [4,256] */,
                        u16* __restrict__ X /* [N,256] */, int N,
                        const int* __restrict__ flag)
{
  int f = *flag;
  int idx = blockIdx.x * blockDim.x + threadIdx.x;
  if (idx >= N * 64) return;
  int n = idx >> 6, c = (idx & 63) * 4;
  int sp = speaker[n];
  ushort4 sv = *(const ushort4*)(spkA + (size_t)sp*256 + c);
  float e0, e1, e2, e3;
  if (f) {
    float4 ev = *(const float4*)((const float*)enc + (size_t)n*256 + c);
    e0 = ev.x; e1 = ev.y; e2 = ev.z; e3 = ev.w;
  } else {
    ushort4 ev = *(const ushort4*)((const u16*)enc + (size_t)n*256 + c);
    e0 = b2f(ev.x); e1 = b2f(ev.y); e2 = b2f(ev.z); e3 = b2f(ev.w);
  }
  ushort4 xv;
  xv.x = f2b(e0 + b2f(sv.x));
  xv.y = f2b(e1 + b2f(sv.y));
  xv.z = f2b(e2 + b2f(sv.z));
  xv.w = f2b(e3 + b2f(sv.w));
  *(ushort4*)(X + (size_t)n*256 + c) = xv;
}

// ---------------- dst-degree histogram ---------------------------------------
__global__ void edge_hist(const int* __restrict__ ei, int* cnt_dst, int E)
{
  int e = blockIdx.x * blockDim.x + threadIdx.x;
  if (e >= E) return;
  atomicAdd(&cnt_dst[ei[E + e]], 1);
}

// ---------------- 3-phase parallel exclusive scan ---------------------------
__global__ void scan_p1(const int* __restrict__ cnt, int* __restrict__ partial,
                        int* __restrict__ bsum, int N)
{
  __shared__ int s[256];
  int t = threadIdx.x;
  int g = blockIdx.x * 256 + t;
  int v = (g < N) ? cnt[g] : 0;
  s[t] = v; __syncthreads();
  #pragma unroll
  for (int off = 1; off < 256; off <<= 1) {
    int u = (t >= off) ? s[t - off] : 0;
    __syncthreads();
    s[t] += u;
    __syncthreads();
  }
  partial[g] = s[t];                       // inclusive
  if (t == 255) bsum[blockIdx.x] = s[255];
}

__global__ void scan_p2(int* __restrict__ bsum, int nb)
{
  __shared__ int s[1024];
  int t = threadIdx.x;
  int v = (t < nb) ? bsum[t] : 0;
  s[t] = v; __syncthreads();
  #pragma unroll
  for (int off = 1; off < 1024; off <<= 1) {
    int u = (t >= off) ? s[t - off] : 0;
    __syncthreads();
    s[t] += u;
    __syncthreads();
  }
  if (t < nb) bsum[t] = s[t] - v;          // exclusive
  if (t == nb - 1) bsum[nb] = s[t];        // total
}

__global__ void scan_p3(const int* __restrict__ cnt, const int* __restrict__ partial,
                        const int* __restrict__ bsum, int* __restrict__ basep, int N)
{
  int g = blockIdx.x * 256 + threadIdx.x;
  if (g < N) basep[g] = partial[g] - cnt[g] + bsum[blockIdx.x];
  if (g == 0) basep[N] = bsum[(N + 255) / 256];
}

// ---------------- scatter edges into dst-sorted order, packed ---------------
__global__ void edge_scatter(const int* __restrict__ ei, const int* __restrict__ et,
                             const int* __restrict__ est, const int* __restrict__ basep,
                             int* cursor, int* __restrict__ esorted, int E)
{
  int e = blockIdx.x * blockDim.x + threadIdx.x;
  if (e >= E) return;
  int d = ei[E + e];
  int pos = basep[d] + atomicAdd(&cursor[d], 1);
  esorted[pos] = ei[e] | (et[e] << 17) | (est[e] << 21);  // src<2^17, 4+4 bits rels
}

// ------- merged RGCN aggregation (conv1+conv3), in-wave rel counts ----------
__global__ __launch_bounds__(256) void rgcn_agg2(
    const int* __restrict__ esorted, const int* __restrict__ basep,
    const u16* __restrict__ X /* [N,256] */,
    const u16* __restrict__ comp1 /* bf16 [16,8] */,
    const u16* __restrict__ comp3 /* bf16 [16,8] */,
    u16* __restrict__ Mix1 /* [CR,2048] */,
    u16* __restrict__ Mix3 /* [CR,2048] */,
    int n0, int CR)
{
  __shared__ float sc1[128], sc3[128];
  if (threadIdx.x < 128) sc1[threadIdx.x] = b2f(comp1[threadIdx.x]);
  else sc3[threadIdx.x - 128] = b2f(comp3[threadIdx.x - 128]);
  __syncthreads();
  int nl = blockIdx.x * 4 + (threadIdx.x >> 6);
  if (nl >= CR) return;
  int n = n0 + nl;
  int lane = threadIdx.x & 63;
  int e0 = basep[n], e1 = basep[n + 1];
  // counting pass: lanes 0-15 count et==lane, lanes 16-31 count est==lane-16
  int myrel = lane & 15;
  int cnt = 0;
  for (int e = e0; e < e1; e++) {
    int rec = esorted[e];
    int r1 = (rec >> 17) & 15, r3 = (rec >> 21) & 15;
    if (lane < 16) cnt += (r1 == myrel);
    else if (lane < 32) cnt += (r3 == myrel);
  }
  float invv = 1.0f / (float)(cnt > 1 ? cnt : 1);
  // main pass
  float acc1[8][4] = {}, acc3[8][4] = {};
  for (int e = e0; e < e1; e++) {
    int rec = esorted[e];
    int src = rec & 0x1FFFF;
    int r1 = (rec >> 17) & 15, r3 = (rec >> 21) & 15;
    float iv1 = __shfl(invv, r1);
    float iv3 = __shfl(invv, 16 + r3);
    ushort4 xr = *(const ushort4*)(X + (size_t)src * 256 + lane * 4);
    float x0 = b2f(xr.x), x1 = b2f(xr.y), x2 = b2f(xr.z), x3 = b2f(xr.w);
    const float* c1p = sc1 + r1 * 8;
    const float* c3p = sc3 + r3 * 8;
    #pragma unroll
    for (int b = 0; b < 8; b++) {
      float w1 = c1p[b] * iv1;
      acc1[b][0] += w1 * x0; acc1[b][1] += w1 * x1;
      acc1[b][2] += w1 * x2; acc1[b][3] += w1 * x3;
      float w3 = c3p[b] * iv3;
      acc3[b][0] += w3 * x0; acc3[b][1] += w3 * x1;
      acc3[b][2] += w3 * x2; acc3[b][3] += w3 * x3;
    }
  }
  #pragma unroll
  for (int b = 0; b < 8; b++) {
    ushort4 o1, o3;
    o1.x = f2b(acc1[b][0]); o1.y = f2b(acc1[b][1]);
    o1.z = f2b(acc1[b][2]); o1.w = f2b(acc1[b][3]);
    o3.x = f2b(acc3[b][0]); o3.y = f2b(acc3[b][1]);
    o3.z = f2b(acc3[b][2]); o3.w = f2b(acc3[b][3]);
    *(ushort4*)(Mix1 + (size_t)nl * 2048 + b * 256 + lane * 4) = o1;
    *(ushort4*)(Mix3 + (size_t)nl * 2048 + b * 256 + lane * 4) = o3;
  }
}

// -------- GraphConv sum-aggregation: 16B/lane, 2 edges per wave-iter --------
__global__ __launch_bounds__(256) void gconv_agg(
    const int* __restrict__ esorted, const int* __restrict__ basep,
    const u16* __restrict__ Hin /* [N,256] */,
    u16* __restrict__ Agg /* [N,256] */, int N)
{
  int n = blockIdx.x * 4 + (threadIdx.x >> 6);
  if (n >= N) return;
  int lane = threadIdx.x & 63;
  int half = lane >> 5, l32 = lane & 31;
  float a[8] = {};
  int e0 = basep[n], e1 = basep[n + 1];
  for (int e = e0; e < e1; e += 2) {
    int ee = e + half;
    bool ok = ee < e1;
    int src = esorted[ok ? ee : e] & 0x1FFFF;
    short8 hv = *(const short8*)(Hin + (size_t)src * 256 + l32 * 8);
    if (ok) {
      #pragma unroll
      for (int j = 0; j < 8; j++) a[j] += b2f((u16)hv[j]);
    }
  }
  #pragma unroll
  for (int j = 0; j < 8; j++) a[j] += __shfl_xor(a[j], 32);
  if (half == 0) {
    short8 o;
    #pragma unroll
    for (int j = 0; j < 8; j++) o[j] = (short)f2b(a[j]);
    *(short8*)(Agg + (size_t)n * 256 + l32 * 8) = o;
  }
}

// ------------- multi-source bf16 MFMA GEMM, 128x32 tiles, reg-prefetch ------
// Depth-2 register pipeline with STATIC buffer sets (a0/b0, a1/b1) and the
// K-loop unrolled x2 (all K multiples of 128) — no dynamic indexing, so the
// buffers live in VGPRs (r8's scratch-spill bug fixed).
__global__ __launch_bounds__(256) void gemm_ms(
    const u16* __restrict__ A0, int lda0,
    const u16* __restrict__ A1, int lda1,
    const u16* __restrict__ A2, int lda2,
    int c1, int c2,
    const u16* __restrict__ Bt, /* [nout, K] */
    const u16* __restrict__ bias,
    u16* __restrict__ Cout, int ldc,
    int M, int K, int relu, int nout, int nx,
    const u16* __restrict__ A0d, const u16* __restrict__ Btd,
    const u16* __restrict__ biasd, u16* __restrict__ Coutd)
{
  constexpr int BK = 64;
  constexpr int LDR = 72;                 // padded row stride (u16)
  __shared__ u16 As[128 * LDR];
  __shared__ u16 Bs[32 * LDR];
  int bi = blockIdx.x;
  const u16* A0u = A0; const u16* Btu = Bt; const u16* biasu = bias;
  u16* Cu = Cout;
  if (bi >= nx) { bi -= nx; A0u = A0d; Btu = Btd; biasu = biasd; Cu = Coutd; }
  int nblk = nout >> 5;
  int grpw = nblk << 3;                   // 8*nblk
  int g = bi / grpw, r = bi % grpw;
  int gm = g * 8 + (r & 7);
  int bm = gm * 128;
  if (bm >= M) return;                    // uniform per block — safe
  int bn = (r >> 3) * 32;

  int tid = threadIdx.x;
  int lane = tid & 63;
  int wid = tid >> 6;
  f32x4 acc[2][2];
  #pragma unroll
  for (int i = 0; i < 2; i++)
    #pragma unroll
    for (int j = 0; j < 2; j++) acc[i][j] = (f32x4)0.0f;

  int sr = tid >> 3;            // 0..31 staging row within group
  int sc = (tid & 7) * 8;       // 0..56 staging col (u16)
  int lm = lane & 15, quad = lane >> 4;

  // precomputed per-lane addresses (bytes advance with k0 directly)
  short8 a0v0, a0v1, a0v2, a0v3, b0v;   // buffer set 0
  short8 a1v0, a1v1, a1v2, a1v3, b1v;   // buffer set 1
  int gr0 = bm + 0 * 32 + sr; gr0 = gr0 < M ? gr0 : M - 1;
  int gr1 = bm + 1 * 32 + sr; gr1 = gr1 < M ? gr1 : M - 1;
  int gr2 = bm + 2 * 32 + sr; gr2 = gr2 < M ? gr2 : M - 1;
  int gr3 = bm + 3 * 32 + sr; gr3 = gr3 < M ? gr3 : M - 1;
  int brr = bn + sr; brr = brr < nout ? brr : nout - 1;
  const u16* bp = Btu + (size_t)brr * K + sc;

#define ISSUE(A_, B_, C_, D_, BB_, K0_)                                        \
  {                                                                            \
    const u16* srcp; int ldas, kO;                                             \
    if ((K0_) < c1)      { srcp = A0u; ldas = lda0; kO = (K0_); }              \
    else if ((K0_) < c2) { srcp = A1;  ldas = lda1; kO = (K0_) - c1; }         \
    else                 { srcp = A2;  ldas = lda2; kO = (K0_) - c2; }         \
    const u16* base = srcp + kO + sc;                                          \
    A_ = *(const short8*)(base + (size_t)gr0 * ldas);                          \
    B_ = *(const short8*)(base + (size_t)gr1 * ldas);                          \
    C_ = *(const short8*)(base + (size_t)gr2 * ldas);                          \
    D_ = *(const short8*)(base + (size_t)gr3 * ldas);                          \
    BB_ = *(const short8*)(bp + (K0_));                                        \
  }

#define STAGE(A_, B_, C_, D_, BB_)                                             \
  {                                                                            \
    *(short8*)(As + (0 * 32 + sr) * LDR + sc) = A_;                            \
    *(short8*)(As + (1 * 32 + sr) * LDR + sc) = B_;                            \
    *(short8*)(As + (2 * 32 + sr) * LDR + sc) = C_;                            \
    *(short8*)(As + (3 * 32 + sr) * LDR + sc) = D_;                            \
    *(short8*)(Bs + sr * LDR + sc) = BB_;                                      \
  }

#define COMPUTE()                                                              \
  {                                                                            \
    _Pragma("unroll")                                                          \
    for (int kk = 0; kk < BK; kk += 32) {                                      \
      short8 af0, af1, bf0, bf1;                                               \
      af0 = *(const short8*)(As + (wid * 32 + lm) * LDR + kk + quad * 8);      \
      af1 = *(const short8*)(As + (wid * 32 + 16 + lm) * LDR + kk + quad * 8); \
      bf0 = *(const short8*)(Bs + lm * LDR + kk + quad * 8);                   \
      bf1 = *(const short8*)(Bs + (16 + lm) * LDR + kk + quad * 8);            \
      acc[0][0] = __builtin_amdgcn_mfma_f32_16x16x32_bf16(af0, bf0, acc[0][0], 0, 0, 0); \
      acc[0][1] = __builtin_amdgcn_mfma_f32_16x16x32_bf16(af0, bf1, acc[0][1], 0, 0, 0); \
      acc[1][0] = __builtin_amdgcn_mfma_f32_16x16x32_bf16(af1, bf0, acc[1][0], 0, 0, 0); \
      acc[1][1] = __builtin_amdgcn_mfma_f32_16x16x32_bf16(af1, bf1, acc[1][1], 0, 0, 0); \
    }                                                                          \
  }

  ISSUE(a0v0, a0v1, a0v2, a0v3, b0v, 0)
  if (K > BK) ISSUE(a1v0, a1v1, a1v2, a1v3, b1v, BK)

  for (int k0 = 0; k0 < K; k0 += 2 * BK) {
    // ---- even half: stage set0, prefetch set0 <- k0+2BK ----
    STAGE(a0v0, a0v1, a0v2, a0v3, b0v)
    if (k0 + 2 * BK < K) ISSUE(a0v0, a0v1, a0v2, a0v3, b0v, k0 + 2 * BK)
    __syncthreads();
    COMPUTE()
    __syncthreads();
    // ---- odd half: stage set1, prefetch set1 <- k0+3BK ----
    if (k0 + BK < K) {
      STAGE(a1v0, a1v1, a1v2, a1v3, b1v)
      if (k0 + 3 * BK < K) ISSUE(a1v0, a1v1, a1v2, a1v3, b1v, k0 + 3 * BK)
      __syncthreads();
      COMPUTE()
      __syncthreads();
    }
  }
#undef ISSUE
#undef STAGE
#undef COMPUTE

  #pragma unroll
  for (int ni = 0; ni < 2; ni++) {
    int gn = bn + ni * 16 + lm;
    float bv = b2f(biasu[gn]);
    #pragma unroll
    for (int mi = 0; mi < 2; mi++) {
      int rbase = bm + wid * 32 + mi * 16 + quad * 4;
      #pragma unroll
      for (int rr = 0; rr < 4; rr++) {
        int gmr = rbase + rr;
        if (gmr < M) {
          float v = acc[mi][ni][rr] + bv;
          if (relu) v = fmaxf(v, 0.f);
          Cu[(size_t)gmr * ldc + gn] = f2b(v);
        }
      }
    }
  }
}

// ---------------- final dot: out[n] = sum_o h2m[n,o]*wd3[o] + bd3 -----------
__global__ __launch_bounds__(256) void mlp_tail2(
    const u16* __restrict__ h2m, const u16* __restrict__ wd3,
    const u16* __restrict__ bd3, void* __restrict__ outp, int N,
    const int* __restrict__ flag)
{
  int n = blockIdx.x * 4 + (threadIdx.x >> 6);
  if (n >= N) return;
  int lane = threadIdx.x & 63;
  float r = b2f(h2m[(size_t)n * 64 + lane]) * b2f(wd3[lane]);
  #pragma unroll
  for (int off = 32; off > 0; off >>= 1) r += __shfl_xor(r, off, 64);
  if (lane == 0) {
    float v = r + b2f(bd3[0]);
    if (*flag) ((float*)outp)[n] = v;
    else       ((u16*)outp)[n] = f2b(v);
  }
}

__global__ void sentinel(u16* out, int n, float code){
  int i = blockIdx.x * blockDim.x + threadIdx.x;
  if (i < n) out[i] = f2b(code);
}

extern "C" void kernel_launch(void* const* d_in, const int* in_sizes, int n_in,
                              void* d_out, int out_size, void* d_ws, size_t ws_size,
                              hipStream_t stream)
{
  const void* enc     = d_in[0];
  const int* speaker  = (const int*)d_in[1];
  const int* ei       = (const int*)d_in[2];
  const int* et       = (const int*)d_in[3];
  const int* est      = (const int*)d_in[4];
  const void* spk_tab = d_in[5];
  const void* comp1   = d_in[6];
  const void* bases1  = d_in[7];
  const void* root1   = d_in[8];
  const void* b1      = d_in[9];
  const void* w2_rel  = d_in[10];
  const void* b2      = d_in[11];
  const void* w2_root = d_in[12];
  const void* comp3   = d_in[13];
  const void* bases3  = d_in[14];
  const void* root3   = d_in[15];
  const void* b3      = d_in[16];
  const void* w4_rel  = d_in[17];
  const void* b4      = d_in[18];
  const void* w4_root = d_in[19];
  const void* wd1     = d_in[20];
  const void* bd1     = d_in[21];
  const void* wd2     = d_in[22];
  const void* bd2     = d_in[23];
  const void* wd3     = d_in[24];
  const void* bd3     = d_in[25];

  int N = in_sizes[1];     // 60000
  int E = in_sizes[3];     // 480000
  int nb = (N + 255) / 256;

  char* ws = (char*)d_ws;
  size_t off = 0;
  auto alloc = [&](size_t bytes) -> char* {
    char* p = ws + off; off = (off + bytes + 255) & ~(size_t)255; return p;
  };
  u16* X    = (u16*)alloc((size_t)N * 256 * 2);   // x = enc+spk; later bf16 enc
  u16* hA   = (u16*)alloc((size_t)N * 256 * 2);   // conv1 rgcn out
  u16* hA3  = (u16*)alloc((size_t)N * 256 * 2);   // conv3 rgcn out
  u16* hB   = (u16*)alloc((size_t)N * 256 * 2);   // h1 final
  u16* hC   = (u16*)alloc((size_t)N * 256 * 2);   // h2 final
  u16* AggB = (u16*)alloc((size_t)N * 256 * 2);   // gconv agg; aliased below
  u16* h1m  = AggB;                                // [N,128] after AggB dead
  u16* h2m  = AggB + (size_t)N * 128;              // [N,64]
  u16* B1t  = (u16*)alloc((size_t)256 * 2304 * 2);
  u16* B3t  = (u16*)alloc((size_t)256 * 2304 * 2);
  u16* B2t  = (u16*)alloc((size_t)256 * 512 * 2);
  u16* B4t  = (u16*)alloc((size_t)256 * 512 * 2);
  u16* D1t  = (u16*)alloc((size_t)128 * 768 * 2);
  u16* arena = (u16*)alloc((size_t)20480 * 2);
  int* flag    = (int*)alloc(256);
  // contiguous zero-init region: cnt_dst, cursor
  int* cnt_dst = (int*)alloc((size_t)N * 4);
  int* cursor  = (int*)alloc((size_t)N * 4);
  size_t zspan = (size_t)((char*)cursor - (char*)cnt_dst) + (size_t)N * 4;
  int* basep   = (int*)alloc((size_t)(N + 1) * 4);
  int* partial = (int*)alloc((size_t)nb * 256 * 4);
  int* bsum    = (int*)alloc((size_t)2048 * 4);
  int* esorted = (int*)alloc((size_t)E * 4);

  // arena layout (u16 offsets)
  u16* spkA   = arena + 0;
  u16* comp1A = arena + 1024;
  u16* comp3A = arena + 1152;
  u16* b1A    = arena + 1280;
  u16* b2A    = arena + 1536;
  u16* b3A    = arena + 1792;
  u16* b4A    = arena + 2048;
  u16* bd1A   = arena + 2304;
  u16* bd2A   = arena + 10624;
  u16* wd3A   = arena + 10688;
  u16* bd3A   = arena + 10752;
  u16* wd2T   = arena + 10880;   // [64,128]

  // Mix1+Mix3 chunk: 8 KB per row
  size_t rem = (ws_size > off) ? (ws_size - off) : 0;
  long crl = (long)(rem / (4096 * 2));
  int chunk_rows = (int)((crl / 128) * 128);
  int Mpad = ((N + 127) / 128) * 128;
  if (chunk_rows > Mpad) chunk_rows = Mpad;

  if (chunk_rows < 128) {
    float code = 2000.0f + (float)(ws_size >> 20);
    sentinel<<<(out_size + 255) / 256, 256, 0, stream>>>((u16*)d_out, out_size, code);
    return;
  }
  u16* Mix1blk = (u16*)(ws + off);
  u16* Mix3blk = Mix1blk + (size_t)chunk_rows * 2048;

  hipMemsetAsync(cnt_dst, 0, zspan, stream);

  detect_dtype<<<1, 256, 0, stream>>>((const u16*)enc, flag);
  cvt_small<<<75, 256, 0, stream>>>(spk_tab, comp1, comp3, b1, b2, b3, b4,
                                    bd1, wd2, bd2, wd3, bd3, arena, flag);

  int totpack = 256*2304*2 + 256*512*2 + 128*768;
  pack_weights<<<(totpack + 255) / 256, 256, 0, stream>>>(
      bases1, root1, w2_rel, w2_root, bases3, root3, w4_rel, w4_root, wd1,
      B1t, B3t, B2t, B4t, D1t, flag);
  build_x<<<(N * 64 + 255) / 256, 256, 0, stream>>>(enc, speaker, spkA, X, N, flag);
  edge_hist<<<(E + 255) / 256, 256, 0, stream>>>(ei, cnt_dst, E);
  scan_p1<<<nb, 256, 0, stream>>>(cnt_dst, partial, bsum, N);
  scan_p2<<<1, 1024, 0, stream>>>(bsum, nb);
  scan_p3<<<nb, 256, 0, stream>>>(cnt_dst, partial, bsum, basep, N);
  edge_scatter<<<(E + 255) / 256, 256, 0, stream>>>(ei, et, est, basep, cursor, esorted, E);

  int nb4 = (N + 3) / 4;
  const u16* nul = (const u16*)nullptr;
  auto nx_for = [](int M_, int nout_) {
    int mg = (M_ + 127) / 128;
    int grpw = (nout_ / 32) * 8;
    return ((mg + 7) / 8) * grpw;
  };

  // convs: merged aggregation + dual GEMM per chunk
  for (int n0 = 0; n0 < N; n0 += chunk_rows) {
    int CR = (N - n0 < chunk_rows) ? (N - n0) : chunk_rows;
    rgcn_agg2<<<(CR + 3) / 4, 256, 0, stream>>>(esorted, basep, X, comp1A, comp3A,
                                                Mix1blk, Mix3blk, n0, CR);
    int nx = nx_for(CR, 256);
    gemm_ms<<<2 * nx, 256, 0, stream>>>(
        Mix1blk, 2048, X + (size_t)n0 * 256, 256, nul, 0, 2048, 2304,
        B1t, b1A, hA + (size_t)n0 * 256, 256, CR, 2304, 0, 256, nx,
        Mix3blk, B3t, b3A, hA3 + (size_t)n0 * 256);
  }
  // gconv2: agg(h1_rgcn) -> [agg|h] @ [w2_rel;w2_root] -> hB
  int nxN = nx_for(N, 256);
  gconv_agg<<<nb4, 256, 0, stream>>>(esorted, basep, hA, AggB, N);
  gemm_ms<<<nxN, 256, 0, stream>>>(
      AggB, 256, hA, 256, nul, 0, 256, 512,
      B2t, b2A, hB, 256, N, 512, 0, 256, nxN, nul, nul, nul, (u16*)nullptr);
  // gconv4
  gconv_agg<<<nb4, 256, 0, stream>>>(esorted, basep, hA3, AggB, N);
  cvt4<<<(N * 64 + 255) / 256, 256, 0, stream>>>(enc, X, N * 256, flag);  // X dead -> bf16 enc
  gemm_ms<<<nxN, 256, 0, stream>>>(
      AggB, 256, hA3, 256, nul, 0, 256, 512,
      B4t, b4A, hC, 256, N, 512, 0, 256, nxN, nul, nul, nul, (u16*)nullptr);

  // MLP layer 1: [enc|h1|h2] @ wd1 (+bd1, relu) -> h1m [N,128]
  int nx1 = nx_for(N, 128);
  gemm_ms<<<nx1, 256, 0, stream>>>(
      X, 256, hB, 256, hC, 256, 256, 512,
      D1t, bd1A, h1m, 128, N, 768, 1, 128, nx1, nul, nul, nul, (u16*)nullptr);
  // MLP layer 2: h1m @ wd2 (+bd2, relu) -> h2m [N,64]
  int nx2 = nx_for(N, 64);
  gemm_ms<<<nx2, 256, 0, stream>>>(
      h1m, 128, nul, 0, nul, 0, 128, 128,
      wd2T, bd2A, h2m, 64, N, 128, 1, 64, nx2, nul, nul, nul, (u16*)nullptr);
  // MLP layer 3
  mlp_tail2<<<nb4, 256, 0, stream>>>(h2m, wd3A, bd3A, d_out, N, flag);
}

// Round 10
// 922.748 us; speedup vs baseline: 35.5201x; 1.0862x over previous
//
#include <hip/hip_runtime.h>
#include <stdint.h>

// PreEncodedGCN on MI355X — round 10.
// vs r9 (single variable): phase-disjoint buffer aliasing. One region R serves
// {sort ints} -> {Mix1+Mix3 chunk} -> {AggB/hB/hC/h1m/h2m}, so the Mix chunk
// grows from ~6.4k to ~18k rows -> 4 chunks, conv GEMM grid ~2304 blocks
// (6-7 resident blocks/CU instead of 3). GEMM kernel unchanged from r9.

typedef unsigned short u16;
typedef __attribute__((ext_vector_type(4))) float f32x4;
typedef __attribute__((ext_vector_type(8))) short short8;

__device__ __forceinline__ float b2f(u16 u){
  union { uint32_t i; float f; } v; v.i = ((uint32_t)u) << 16; return v.f;
}
__device__ __forceinline__ u16 f2b(float f){
  union { float f; uint32_t i; } v; v.f = f;
  uint32_t u = v.i;
  return (u16)((u + 0x7FFFu + ((u >> 16) & 1u)) >> 16);
}
__device__ __forceinline__ u16 rdw(const void* p, size_t i, int f32){
  return f32 ? f2b(((const float*)p)[i]) : ((const u16*)p)[i];
}

// ---------------- dtype detector: 1 = fp32, 0 = bf16 ------------------------
__global__ void detect_dtype(const u16* enc16, int* flag){
  __shared__ int cnt;
  if (threadIdx.x == 0) cnt = 0;
  __syncthreads();
  unsigned u = enc16[threadIdx.x * 2];
  int e = (u >> 7) & 0xFF;
  if (e >= 100 && e <= 140) atomicAdd(&cnt, 1);
  __syncthreads();
  if (threadIdx.x == 0) flag[0] = (cnt < 128) ? 1 : 0;
}

// ---------------- batched small-weight conversion ---------------------------
// arena u16 offsets: spk@0(1024) c1@1024(128) c3@1152(128) b1@1280 b2@1536
// b3@1792 b4@2048(256ea) bd1@2304(128) bd2@10624(64) wd3@10688(64)
// bd3@10752(1) wd2T@10880(8192, [o*128+k])
__global__ void cvt_small(const void* spk, const void* c1, const void* c3,
                          const void* b1, const void* b2, const void* b3,
                          const void* b4, const void* bd1, const void* wd2,
                          const void* bd2, const void* wd3, const void* bd3,
                          u16* __restrict__ arena, const int* __restrict__ flag)
{
  int f = *flag;
  int i = blockIdx.x * blockDim.x + threadIdx.x;
  if (i < 1024) { arena[i] = rdw(spk, i, f); return; } i -= 1024;
  if (i < 128)  { arena[1024 + i] = rdw(c1, i, f); return; } i -= 128;
  if (i < 128)  { arena[1152 + i] = rdw(c3, i, f); return; } i -= 128;
  if (i < 256)  { arena[1280 + i] = rdw(b1, i, f); return; } i -= 256;
  if (i < 256)  { arena[1536 + i] = rdw(b2, i, f); return; } i -= 256;
  if (i < 256)  { arena[1792 + i] = rdw(b3, i, f); return; } i -= 256;
  if (i < 256)  { arena[2048 + i] = rdw(b4, i, f); return; } i -= 256;
  if (i < 128)  { arena[2304 + i] = rdw(bd1, i, f); return; } i -= 128;
  if (i < 64)   { arena[10624 + i] = rdw(bd2, i, f); return; } i -= 64;
  if (i < 64)   { arena[10688 + i] = rdw(wd3, i, f); return; } i -= 64;
  if (i < 1)    { arena[10752 + i] = rdw(bd3, i, f); return; } i -= 1;
  if (i < 8192) { int o = i >> 7, k = i & 127;          // wd2T[o,k] = wd2[k,o]
    arena[10880 + i] = rdw(wd2, k * 64 + o, f); }
}

// ---------------- vectorized convert (n multiple of 4) ----------------------
__global__ void cvt4(const void* __restrict__ in, u16* __restrict__ out, int n,
                     const int* __restrict__ flag){
  int i = (blockIdx.x * blockDim.x + threadIdx.x) * 4;
  if (i >= n) return;
  ushort4 o;
  if (*flag) {
    float4 v = *(const float4*)((const float*)in + i);
    o.x = f2b(v.x); o.y = f2b(v.y); o.z = f2b(v.z); o.w = f2b(v.w);
  } else {
    o = *(const ushort4*)((const u16*)in + i);
  }
  *(ushort4*)(out + i) = o;
}

// ---------------- weight packing: transpose B matrices to [NOUT, K] ----------
__global__ void pack_weights(const void* __restrict__ bases1, const void* __restrict__ root1,
                             const void* __restrict__ w2_rel, const void* __restrict__ w2_root,
                             const void* __restrict__ bases3, const void* __restrict__ root3,
                             const void* __restrict__ w4_rel, const void* __restrict__ w4_root,
                             const void* __restrict__ wd1,
                             u16* __restrict__ B1t, u16* __restrict__ B3t,
                             u16* __restrict__ B2t, u16* __restrict__ B4t,
                             u16* __restrict__ D1t, const int* __restrict__ flag)
{
  int f = *flag;
  int idx = blockIdx.x * blockDim.x + threadIdx.x;
  if (idx < 256*2304) { int o = idx / 2304, k = idx % 2304;
    B1t[idx] = (k < 2048) ? rdw(bases1, k*256 + o, f) : rdw(root1, (k-2048)*256 + o, f); return; }
  idx -= 256*2304;
  if (idx < 256*2304) { int o = idx / 2304, k = idx % 2304;
    B3t[idx] = (k < 2048) ? rdw(bases3, k*256 + o, f) : rdw(root3, (k-2048)*256 + o, f); return; }
  idx -= 256*2304;
  if (idx < 256*512) { int o = idx / 512, k = idx % 512;
    B2t[idx] = (k < 256) ? rdw(w2_rel, k*256 + o, f) : rdw(w2_root, (k-256)*256 + o, f); return; }
  idx -= 256*512;
  if (idx < 256*512) { int o = idx / 512, k = idx % 512;
    B4t[idx] = (k < 256) ? rdw(w4_rel, k*256 + o, f) : rdw(w4_root, (k-256)*256 + o, f); return; }
  idx -= 256*512;
  if (idx < 128*768) { int o = idx / 768, k = idx % 768;
    D1t[idx] = rdw(wd1, k*128 + o, f); }
}

// ---------------- x = encoding + spk_table[speaker] -------------------------
__global__ void build_x(const void* __restrict__ enc, const int* __restrict__ speaker,
                        const u16* __restrict__ spkA /* bf16 [4,256] */,
                        u16* __restrict__ X /* [N,256] */, int N,
                        const int* __restrict__ flag)
{
  int f = *flag;
  int idx = blockIdx.x * blockDim.x + threadIdx.x;
  if (idx >= N * 64) return;
  int n = idx >> 6, c = (idx & 63) * 4;
  int sp = speaker[n];
  ushort4 sv = *(const ushort4*)(spkA + (size_t)sp*256 + c);
  float e0, e1, e2, e3;
  if (f) {
    float4 ev = *(const float4*)((const float*)enc + (size_t)n*256 + c);
    e0 = ev.x; e1 = ev.y; e2 = ev.z; e3 = ev.w;
  } else {
    ushort4 ev = *(const ushort4*)((const u16*)enc + (size_t)n*256 + c);
    e0 = b2f(ev.x); e1 = b2f(ev.y); e2 = b2f(ev.z); e3 = b2f(ev.w);
  }
  ushort4 xv;
  xv.x = f2b(e0 + b2f(sv.x));
  xv.y = f2b(e1 + b2f(sv.y));
  xv.z = f2b(e2 + b2f(sv.z));
  xv.w = f2b(e3 + b2f(sv.w));
  *(ushort4*)(X + (size_t)n*256 + c) = xv;
}

// ---------------- dst-degree histogram ---------------------------------------
__global__ void edge_hist(const int* __restrict__ ei, int* cnt_dst, int E)
{
  int e = blockIdx.x * blockDim.x + threadIdx.x;
  if (e >= E) return;
  atomicAdd(&cnt_dst[ei[E + e]], 1);
}

// ---------------- 3-phase parallel exclusive scan ---------------------------
__global__ void scan_p1(const int* __restrict__ cnt, int* __restrict__ partial,
                        int* __restrict__ bsum, int N)
{
  __shared__ int s[256];
  int t = threadIdx.x;
  int g = blockIdx.x * 256 + t;
  int v = (g < N) ? cnt[g] : 0;
  s[t] = v; __syncthreads();
  #pragma unroll
  for (int off = 1; off < 256; off <<= 1) {
    int u = (t >= off) ? s[t - off] : 0;
    __syncthreads();
    s[t] += u;
    __syncthreads();
  }
  partial[g] = s[t];                       // inclusive
  if (t == 255) bsum[blockIdx.x] = s[255];
}

__global__ void scan_p2(int* __restrict__ bsum, int nb)
{
  __shared__ int s[1024];
  int t = threadIdx.x;
  int v = (t < nb) ? bsum[t] : 0;
  s[t] = v; __syncthreads();
  #pragma unroll
  for (int off = 1; off < 1024; off <<= 1) {
    int u = (t >= off) ? s[t - off] : 0;
    __syncthreads();
    s[t] += u;
    __syncthreads();
  }
  if (t < nb) bsum[t] = s[t] - v;          // exclusive
  if (t == nb - 1) bsum[nb] = s[t];        // total
}

__global__ void scan_p3(const int* __restrict__ cnt, const int* __restrict__ partial,
                        const int* __restrict__ bsum, int* __restrict__ basep, int N)
{
  int g = blockIdx.x * 256 + threadIdx.x;
  if (g < N) basep[g] = partial[g] - cnt[g] + bsum[blockIdx.x];
  if (g == 0) basep[N] = bsum[(N + 255) / 256];
}

// ---------------- scatter edges into dst-sorted order, packed ---------------
__global__ void edge_scatter(const int* __restrict__ ei, const int* __restrict__ et,
                             const int* __restrict__ est, const int* __restrict__ basep,
                             int* cursor, int* __restrict__ esorted, int E)
{
  int e = blockIdx.x * blockDim.x + threadIdx.x;
  if (e >= E) return;
  int d = ei[E + e];
  int pos = basep[d] + atomicAdd(&cursor[d], 1);
  esorted[pos] = ei[e] | (et[e] << 17) | (est[e] << 21);  // src<2^17, 4+4 bits rels
}

// ------- merged RGCN aggregation (conv1+conv3), in-wave rel counts ----------
__global__ __launch_bounds__(256) void rgcn_agg2(
    const int* __restrict__ esorted, const int* __restrict__ basep,
    const u16* __restrict__ X /* [N,256] */,
    const u16* __restrict__ comp1 /* bf16 [16,8] */,
    const u16* __restrict__ comp3 /* bf16 [16,8] */,
    u16* __restrict__ Mix1 /* [CR,2048] */,
    u16* __restrict__ Mix3 /* [CR,2048] */,
    int n0, int CR)
{
  __shared__ float sc1[128], sc3[128];
  if (threadIdx.x < 128) sc1[threadIdx.x] = b2f(comp1[threadIdx.x]);
  else sc3[threadIdx.x - 128] = b2f(comp3[threadIdx.x - 128]);
  __syncthreads();
  int nl = blockIdx.x * 4 + (threadIdx.x >> 6);
  if (nl >= CR) return;
  int n = n0 + nl;
  int lane = threadIdx.x & 63;
  int e0 = basep[n], e1 = basep[n + 1];
  // counting pass: lanes 0-15 count et==lane, lanes 16-31 count est==lane-16
  int myrel = lane & 15;
  int cnt = 0;
  for (int e = e0; e < e1; e++) {
    int rec = esorted[e];
    int r1 = (rec >> 17) & 15, r3 = (rec >> 21) & 15;
    if (lane < 16) cnt += (r1 == myrel);
    else if (lane < 32) cnt += (r3 == myrel);
  }
  float invv = 1.0f / (float)(cnt > 1 ? cnt : 1);
  // main pass
  float acc1[8][4] = {}, acc3[8][4] = {};
  for (int e = e0; e < e1; e++) {
    int rec = esorted[e];
    int src = rec & 0x1FFFF;
    int r1 = (rec >> 17) & 15, r3 = (rec >> 21) & 15;
    float iv1 = __shfl(invv, r1);
    float iv3 = __shfl(invv, 16 + r3);
    ushort4 xr = *(const ushort4*)(X + (size_t)src * 256 + lane * 4);
    float x0 = b2f(xr.x), x1 = b2f(xr.y), x2 = b2f(xr.z), x3 = b2f(xr.w);
    const float* c1p = sc1 + r1 * 8;
    const float* c3p = sc3 + r3 * 8;
    #pragma unroll
    for (int b = 0; b < 8; b++) {
      float w1 = c1p[b] * iv1;
      acc1[b][0] += w1 * x0; acc1[b][1] += w1 * x1;
      acc1[b][2] += w1 * x2; acc1[b][3] += w1 * x3;
      float w3 = c3p[b] * iv3;
      acc3[b][0] += w3 * x0; acc3[b][1] += w3 * x1;
      acc3[b][2] += w3 * x2; acc3[b][3] += w3 * x3;
    }
  }
  #pragma unroll
  for (int b = 0; b < 8; b++) {
    ushort4 o1, o3;
    o1.x = f2b(acc1[b][0]); o1.y = f2b(acc1[b][1]);
    o1.z = f2b(acc1[b][2]); o1.w = f2b(acc1[b][3]);
    o3.x = f2b(acc3[b][0]); o3.y = f2b(acc3[b][1]);
    o3.z = f2b(acc3[b][2]); o3.w = f2b(acc3[b][3]);
    *(ushort4*)(Mix1 + (size_t)nl * 2048 + b * 256 + lane * 4) = o1;
    *(ushort4*)(Mix3 + (size_t)nl * 2048 + b * 256 + lane * 4) = o3;
  }
}

// -------- GraphConv sum-aggregation: 16B/lane, 2 edges per wave-iter --------
__global__ __launch_bounds__(256) void gconv_agg(
    const int* __restrict__ esorted, const int* __restrict__ basep,
    const u16* __restrict__ Hin /* [N,256] */,
    u16* __restrict__ Agg /* [N,256] */, int N)
{
  int n = blockIdx.x * 4 + (threadIdx.x >> 6);
  if (n >= N) return;
  int lane = threadIdx.x & 63;
  int half = lane >> 5, l32 = lane & 31;
  float a[8] = {};
  int e0 = basep[n], e1 = basep[n + 1];
  for (int e = e0; e < e1; e += 2) {
    int ee = e + half;
    bool ok = ee < e1;
    int src = esorted[ok ? ee : e] & 0x1FFFF;
    short8 hv = *(const short8*)(Hin + (size_t)src * 256 + l32 * 8);
    if (ok) {
      #pragma unroll
      for (int j = 0; j < 8; j++) a[j] += b2f((u16)hv[j]);
    }
  }
  #pragma unroll
  for (int j = 0; j < 8; j++) a[j] += __shfl_xor(a[j], 32);
  if (half == 0) {
    short8 o;
    #pragma unroll
    for (int j = 0; j < 8; j++) o[j] = (short)f2b(a[j]);
    *(short8*)(Agg + (size_t)n * 256 + l32 * 8) = o;
  }
}

// ------------- multi-source bf16 MFMA GEMM, 128x32 tiles, reg-prefetch ------
// Identical to r9: depth-2 static-register prefetch pipeline.
__global__ __launch_bounds__(256) void gemm_ms(
    const u16* __restrict__ A0, int lda0,
    const u16* __restrict__ A1, int lda1,
    const u16* __restrict__ A2, int lda2,
    int c1, int c2,
    const u16* __restrict__ Bt, /* [nout, K] */
    const u16* __restrict__ bias,
    u16* __restrict__ Cout, int ldc,
    int M, int K, int relu, int nout, int nx,
    const u16* __restrict__ A0d, const u16* __restrict__ Btd,
    const u16* __restrict__ biasd, u16* __restrict__ Coutd)
{
  constexpr int BK = 64;
  constexpr int LDR = 72;                 // padded row stride (u16)
  __shared__ u16 As[128 * LDR];
  __shared__ u16 Bs[32 * LDR];
  int bi = blockIdx.x;
  const u16* A0u = A0; const u16* Btu = Bt; const u16* biasu = bias;
  u16* Cu = Cout;
  if (bi >= nx) { bi -= nx; A0u = A0d; Btu = Btd; biasu = biasd; Cu = Coutd; }
  int nblk = nout >> 5;
  int grpw = nblk << 3;                   // 8*nblk
  int g = bi / grpw, r = bi % grpw;
  int gm = g * 8 + (r & 7);
  int bm = gm * 128;
  if (bm >= M) return;                    // uniform per block — safe
  int bn = (r >> 3) * 32;

  int tid = threadIdx.x;
  int lane = tid & 63;
  int wid = tid >> 6;
  f32x4 acc[2][2];
  #pragma unroll
  for (int i = 0; i < 2; i++)
    #pragma unroll
    for (int j = 0; j < 2; j++) acc[i][j] = (f32x4)0.0f;

  int sr = tid >> 3;            // 0..31 staging row within group
  int sc = (tid & 7) * 8;       // 0..56 staging col (u16)
  int lm = lane & 15, quad = lane >> 4;

  short8 a0v0, a0v1, a0v2, a0v3, b0v;   // buffer set 0
  short8 a1v0, a1v1, a1v2, a1v3, b1v;   // buffer set 1
  int gr0 = bm + 0 * 32 + sr; gr0 = gr0 < M ? gr0 : M - 1;
  int gr1 = bm + 1 * 32 + sr; gr1 = gr1 < M ? gr1 : M - 1;
  int gr2 = bm + 2 * 32 + sr; gr2 = gr2 < M ? gr2 : M - 1;
  int gr3 = bm + 3 * 32 + sr; gr3 = gr3 < M ? gr3 : M - 1;
  int brr = bn + sr; brr = brr < nout ? brr : nout - 1;
  const u16* bp = Btu + (size_t)brr * K + sc;

#define ISSUE(A_, B_, C_, D_, BB_, K0_)                                        \
  {                                                                            \
    const u16* srcp; int ldas, kO;                                             \
    if ((K0_) < c1)      { srcp = A0u; ldas = lda0; kO = (K0_); }              \
    else if ((K0_) < c2) { srcp = A1;  ldas = lda1; kO = (K0_) - c1; }         \
    else                 { srcp = A2;  ldas = lda2; kO = (K0_) - c2; }         \
    const u16* base = srcp + kO + sc;                                          \
    A_ = *(const short8*)(base + (size_t)gr0 * ldas);                          \
    B_ = *(const short8*)(base + (size_t)gr1 * ldas);                          \
    C_ = *(const short8*)(base + (size_t)gr2 * ldas);                          \
    D_ = *(const short8*)(base + (size_t)gr3 * ldas);                          \
    BB_ = *(const short8*)(bp + (K0_));                                        \
  }

#define STAGE(A_, B_, C_, D_, BB_)                                             \
  {                                                                            \
    *(short8*)(As + (0 * 32 + sr) * LDR + sc) = A_;                            \
    *(short8*)(As + (1 * 32 + sr) * LDR + sc) = B_;                            \
    *(short8*)(As + (2 * 32 + sr) * LDR + sc) = C_;                            \
    *(short8*)(As + (3 * 32 + sr) * LDR + sc) = D_;                            \
    *(short8*)(Bs + sr * LDR + sc) = BB_;                                      \
  }

#define COMPUTE()                                                              \
  {                                                                            \
    _Pragma("unroll")                                                          \
    for (int kk = 0; kk < BK; kk += 32) {                                      \
      short8 af0, af1, bf0, bf1;                                               \
      af0 = *(const short8*)(As + (wid * 32 + lm) * LDR + kk + quad * 8);      \
      af1 = *(const short8*)(As + (wid * 32 + 16 + lm) * LDR + kk + quad * 8); \
      bf0 = *(const short8*)(Bs + lm * LDR + kk + quad * 8);                   \
      bf1 = *(const short8*)(Bs + (16 + lm) * LDR + kk + quad * 8);            \
      acc[0][0] = __builtin_amdgcn_mfma_f32_16x16x32_bf16(af0, bf0, acc[0][0], 0, 0, 0); \
      acc[0][1] = __builtin_amdgcn_mfma_f32_16x16x32_bf16(af0, bf1, acc[0][1], 0, 0, 0); \
      acc[1][0] = __builtin_amdgcn_mfma_f32_16x16x32_bf16(af1, bf0, acc[1][0], 0, 0, 0); \
      acc[1][1] = __builtin_amdgcn_mfma_f32_16x16x32_bf16(af1, bf1, acc[1][1], 0, 0, 0); \
    }                                                                          \
  }

  ISSUE(a0v0, a0v1, a0v2, a0v3, b0v, 0)
  if (K > BK) ISSUE(a1v0, a1v1, a1v2, a1v3, b1v, BK)

  for (int k0 = 0; k0 < K; k0 += 2 * BK) {
    STAGE(a0v0, a0v1, a0v2, a0v3, b0v)
    if (k0 + 2 * BK < K) ISSUE(a0v0, a0v1, a0v2, a0v3, b0v, k0 + 2 * BK)
    __syncthreads();
    COMPUTE()
    __syncthreads();
    if (k0 + BK < K) {
      STAGE(a1v0, a1v1, a1v2, a1v3, b1v)
      if (k0 + 3 * BK < K) ISSUE(a1v0, a1v1, a1v2, a1v3, b1v, k0 + 3 * BK)
      __syncthreads();
      COMPUTE()
      __syncthreads();
    }
  }
#undef ISSUE
#undef STAGE
#undef COMPUTE

  #pragma unroll
  for (int ni = 0; ni < 2; ni++) {
    int gn = bn + ni * 16 + lm;
    float bv = b2f(biasu[gn]);
    #pragma unroll
    for (int mi = 0; mi < 2; mi++) {
      int rbase = bm + wid * 32 + mi * 16 + quad * 4;
      #pragma unroll
      for (int rr = 0; rr < 4; rr++) {
        int gmr = rbase + rr;
        if (gmr < M) {
          float v = acc[mi][ni][rr] + bv;
          if (relu) v = fmaxf(v, 0.f);
          Cu[(size_t)gmr * ldc + gn] = f2b(v);
        }
      }
    }
  }
}

// ---------------- final dot: out[n] = sum_o h2m[n,o]*wd3[o] + bd3 -----------
__global__ __launch_bounds__(256) void mlp_tail2(
    const u16* __restrict__ h2m, const u16* __restrict__ wd3,
    const u16* __restrict__ bd3, void* __restrict__ outp, int N,
    const int* __restrict__ flag)
{
  int n = blockIdx.x * 4 + (threadIdx.x >> 6);
  if (n >= N) return;
  int lane = threadIdx.x & 63;
  float r = b2f(h2m[(size_t)n * 64 + lane]) * b2f(wd3[lane]);
  #pragma unroll
  for (int off = 32; off > 0; off >>= 1) r += __shfl_xor(r, off, 64);
  if (lane == 0) {
    float v = r + b2f(bd3[0]);
    if (*flag) ((float*)outp)[n] = v;
    else       ((u16*)outp)[n] = f2b(v);
  }
}

__global__ void sentinel(u16* out, int n, float code){
  int i = blockIdx.x * blockDim.x + threadIdx.x;
  if (i < n) out[i] = f2b(code);
}

extern "C" void kernel_launch(void* const* d_in, const int* in_sizes, int n_in,
                              void* d_out, int out_size, void* d_ws, size_t ws_size,
                              hipStream_t stream)
{
  const void* enc     = d_in[0];
  const int* speaker  = (const int*)d_in[1];
  const int* ei       = (const int*)d_in[2];
  const int* et       = (const int*)d_in[3];
  const int* est      = (const int*)d_in[4];
  const void* spk_tab = d_in[5];
  const void* comp1   = d_in[6];
  const void* bases1  = d_in[7];
  const void* root1   = d_in[8];
  const void* b1      = d_in[9];
  const void* w2_rel  = d_in[10];
  const void* b2      = d_in[11];
  const void* w2_root = d_in[12];
  const void* comp3   = d_in[13];
  const void* bases3  = d_in[14];
  const void* root3   = d_in[15];
  const void* b3      = d_in[16];
  const void* w4_rel  = d_in[17];
  const void* b4      = d_in[18];
  const void* w4_root = d_in[19];
  const void* wd1     = d_in[20];
  const void* bd1     = d_in[21];
  const void* wd2     = d_in[22];
  const void* bd2     = d_in[23];
  const void* wd3     = d_in[24];
  const void* bd3     = d_in[25];

  int N = in_sizes[1];     // 60000
  int E = in_sizes[3];     // 480000
  int nb = (N + 255) / 256;

  char* ws = (char*)d_ws;
  size_t off = 0;
  auto alloc = [&](size_t bytes) -> char* {
    char* p = ws + off; off = (off + bytes + 255) & ~(size_t)255; return p;
  };
  // ---- fixed pool (live across phases) ----
  u16* X    = (u16*)alloc((size_t)N * 256 * 2);   // x = enc+spk; later bf16 enc
  u16* hA   = (u16*)alloc((size_t)N * 256 * 2);   // conv1 rgcn out
  u16* hA3  = (u16*)alloc((size_t)N * 256 * 2);   // conv3 rgcn out
  u16* B1t  = (u16*)alloc((size_t)256 * 2304 * 2);
  u16* B3t  = (u16*)alloc((size_t)256 * 2304 * 2);
  u16* B2t  = (u16*)alloc((size_t)256 * 512 * 2);
  u16* B4t  = (u16*)alloc((size_t)256 * 512 * 2);
  u16* D1t  = (u16*)alloc((size_t)128 * 768 * 2);
  u16* arena = (u16*)alloc((size_t)20480 * 2);
  int* flag    = (int*)alloc(256);
  int* basep   = (int*)alloc((size_t)(N + 1) * 4);
  int* esorted = (int*)alloc((size_t)E * 4);

  // ---- phase-overlaid region R (everything below is time-disjoint) ----
  // phase 0 (sort): cnt_dst, cursor, partial, bsum
  // phase 1 (convs): Mix1+Mix3 chunk
  // phase 2 (gconv/MLP): AggB, hB, hC (h1m/h2m alias AggB)
  char* R = ws + off;
  size_t Rsize = (ws_size > off) ? (ws_size - off) : 0;

  int* cnt_dst = (int*)R;
  int* cursor  = (int*)(R + (size_t)N * 4);
  int* partial = (int*)(R + (size_t)2 * N * 4);
  int* bsum    = (int*)(R + (size_t)2 * N * 4 + (size_t)nb * 256 * 4);
  size_t zspan = (size_t)2 * N * 4;               // cnt_dst + cursor

  u16* AggB = (u16*)R;                            // phase 2
  u16* hB   = (u16*)(R + (size_t)N * 256 * 2);
  u16* hC   = (u16*)(R + (size_t)2 * N * 256 * 2);
  u16* h1m  = AggB;                               // [N,128]
  u16* h2m  = AggB + (size_t)N * 128;             // [N,64]
  size_t phase2_need = (size_t)3 * N * 256 * 2;

  // Mix chunk sizing: 8 KB per row (Mix1+Mix3)
  long crl = (long)(Rsize / (4096 * 2));
  int chunk_rows = (int)((crl / 128) * 128);
  int Mpad = ((N + 127) / 128) * 128;
  if (chunk_rows > Mpad) chunk_rows = Mpad;

  size_t sort_need = (size_t)2 * N * 4 + (size_t)nb * 256 * 4 + 2048 * 4;
  if (chunk_rows < 128 || Rsize < phase2_need || Rsize < sort_need) {
    float code = 2000.0f + (float)(ws_size >> 20);
    sentinel<<<(out_size + 255) / 256, 256, 0, stream>>>((u16*)d_out, out_size, code);
    return;
  }
  u16* Mix1blk = (u16*)R;                         // phase 1
  u16* Mix3blk = Mix1blk + (size_t)chunk_rows * 2048;

  // arena layout (u16 offsets)
  u16* spkA   = arena + 0;
  u16* comp1A = arena + 1024;
  u16* comp3A = arena + 1152;
  u16* b1A    = arena + 1280;
  u16* b2A    = arena + 1536;
  u16* b3A    = arena + 1792;
  u16* b4A    = arena + 2048;
  u16* bd1A   = arena + 2304;
  u16* bd2A   = arena + 10624;
  u16* wd3A   = arena + 10688;
  u16* bd3A   = arena + 10752;
  u16* wd2T   = arena + 10880;   // [64,128]

  hipMemsetAsync(cnt_dst, 0, zspan, stream);

  detect_dtype<<<1, 256, 0, stream>>>((const u16*)enc, flag);
  cvt_small<<<75, 256, 0, stream>>>(spk_tab, comp1, comp3, b1, b2, b3, b4,
                                    bd1, wd2, bd2, wd3, bd3, arena, flag);

  int totpack = 256*2304*2 + 256*512*2 + 128*768;
  pack_weights<<<(totpack + 255) / 256, 256, 0, stream>>>(
      bases1, root1, w2_rel, w2_root, bases3, root3, w4_rel, w4_root, wd1,
      B1t, B3t, B2t, B4t, D1t, flag);
  build_x<<<(N * 64 + 255) / 256, 256, 0, stream>>>(enc, speaker, spkA, X, N, flag);
  edge_hist<<<(E + 255) / 256, 256, 0, stream>>>(ei, cnt_dst, E);
  scan_p1<<<nb, 256, 0, stream>>>(cnt_dst, partial, bsum, N);
  scan_p2<<<1, 1024, 0, stream>>>(bsum, nb);
  scan_p3<<<nb, 256, 0, stream>>>(cnt_dst, partial, bsum, basep, N);
  edge_scatter<<<(E + 255) / 256, 256, 0, stream>>>(ei, et, est, basep, cursor, esorted, E);

  int nb4 = (N + 3) / 4;
  const u16* nul = (const u16*)nullptr;
  auto nx_for = [](int M_, int nout_) {
    int mg = (M_ + 127) / 128;
    int grpw = (nout_ / 32) * 8;
    return ((mg + 7) / 8) * grpw;
  };

  // phase 1 — convs: merged aggregation + dual GEMM per chunk
  for (int n0 = 0; n0 < N; n0 += chunk_rows) {
    int CR = (N - n0 < chunk_rows) ? (N - n0) : chunk_rows;
    rgcn_agg2<<<(CR + 3) / 4, 256, 0, stream>>>(esorted, basep, X, comp1A, comp3A,
                                                Mix1blk, Mix3blk, n0, CR);
    int nx = nx_for(CR, 256);
    gemm_ms<<<2 * nx, 256, 0, stream>>>(
        Mix1blk, 2048, X + (size_t)n0 * 256, 256, nul, 0, 2048, 2304,
        B1t, b1A, hA + (size_t)n0 * 256, 256, CR, 2304, 0, 256, nx,
        Mix3blk, B3t, b3A, hA3 + (size_t)n0 * 256);
  }
  // phase 2 — gconv2: agg(h1_rgcn) -> [agg|h] @ [w2_rel;w2_root] -> hB
  int nxN = nx_for(N, 256);
  gconv_agg<<<nb4, 256, 0, stream>>>(esorted, basep, hA, AggB, N);
  gemm_ms<<<nxN, 256, 0, stream>>>(
      AggB, 256, hA, 256, nul, 0, 256, 512,
      B2t, b2A, hB, 256, N, 512, 0, 256, nxN, nul, nul, nul, (u16*)nullptr);
  // gconv4
  gconv_agg<<<nb4, 256, 0, stream>>>(esorted, basep, hA3, AggB, N);
  cvt4<<<(N * 64 + 255) / 256, 256, 0, stream>>>(enc, X, N * 256, flag);  // X dead -> bf16 enc
  gemm_ms<<<nxN, 256, 0, stream>>>(
      AggB, 256, hA3, 256, nul, 0, 256, 512,
      B4t, b4A, hC, 256, N, 512, 0, 256, nxN, nul, nul, nul, (u16*)nullptr);

  // MLP layer 1: [enc|h1|h2] @ wd1 (+bd1, relu) -> h1m [N,128]
  int nx1 = nx_for(N, 128);
  gemm_ms<<<nx1, 256, 0, stream>>>(
      X, 256, hB, 256, hC, 256, 256, 512,
      D1t, bd1A, h1m, 128, N, 768, 1, 128, nx1, nul, nul, nul, (u16*)nullptr);
  // MLP layer 2: h1m @ wd2 (+bd2, relu) -> h2m [N,64]
  int nx2 = nx_for(N, 64);
  gemm_ms<<<nx2, 256, 0, stream>>>(
      h1m, 128, nul, 0, nul, 0, 128, 128,
      wd2T, bd2A, h2m, 64, N, 128, 1, 64, nx2, nul, nul, nul, (u16*)nullptr);
  // MLP layer 3
  mlp_tail2<<<nb4, 256, 0, stream>>>(h2m, wd3A, bd3A, d_out, N, flag);
}

// Round 11
// 792.785 us; speedup vs baseline: 41.3430x; 1.1639x over previous
//
#include <hip/hip_runtime.h>
#include <stdint.h>

// PreEncodedGCN on MI355X — round 11.
// vs r10 (single variable): gemm_ms rewritten to the m97 structure —
// 128x128 tile, 64x64 per wave, BK=64, global_load_lds(16B) staging with
// XOR-swizzled fetch (linear lane-order LDS writes = conflict-free; swizzled
// reads span all 32 banks). Removes all ds_write instructions from the wave
// stream and the 12M bank-conflict cycles. r2's version of this was likely
// never broken (its zeros were the fp32-dtype bug fixed in r4).

typedef unsigned short u16;
typedef __attribute__((ext_vector_type(4))) float f32x4;
typedef __attribute__((ext_vector_type(8))) short short8;

__device__ __forceinline__ float b2f(u16 u){
  union { uint32_t i; float f; } v; v.i = ((uint32_t)u) << 16; return v.f;
}
__device__ __forceinline__ u16 f2b(float f){
  union { float f; uint32_t i; } v; v.f = f;
  uint32_t u = v.i;
  return (u16)((u + 0x7FFFu + ((u >> 16) & 1u)) >> 16);
}
__device__ __forceinline__ u16 rdw(const void* p, size_t i, int f32){
  return f32 ? f2b(((const float*)p)[i]) : ((const u16*)p)[i];
}
__device__ __forceinline__ void gload_lds16(const u16* gp, u16* lp){
  __builtin_amdgcn_global_load_lds(
      (const __attribute__((address_space(1))) uint32_t*)(uintptr_t)gp,
      (__attribute__((address_space(3))) uint32_t*)lp, 16, 0, 0);
}

// ---------------- dtype detector: 1 = fp32, 0 = bf16 ------------------------
__global__ void detect_dtype(const u16* enc16, int* flag){
  __shared__ int cnt;
  if (threadIdx.x == 0) cnt = 0;
  __syncthreads();
  unsigned u = enc16[threadIdx.x * 2];
  int e = (u >> 7) & 0xFF;
  if (e >= 100 && e <= 140) atomicAdd(&cnt, 1);
  __syncthreads();
  if (threadIdx.x == 0) flag[0] = (cnt < 128) ? 1 : 0;
}

// ---------------- batched small-weight conversion ---------------------------
// arena u16 offsets: spk@0(1024) c1@1024(128) c3@1152(128) b1@1280 b2@1536
// b3@1792 b4@2048(256ea) bd1@2304(128) bd2@10624(64) wd3@10688(64)
// bd3@10752(1) wd2T@10880(8192, [o*128+k])
__global__ void cvt_small(const void* spk, const void* c1, const void* c3,
                          const void* b1, const void* b2, const void* b3,
                          const void* b4, const void* bd1, const void* wd2,
                          const void* bd2, const void* wd3, const void* bd3,
                          u16* __restrict__ arena, const int* __restrict__ flag)
{
  int f = *flag;
  int i = blockIdx.x * blockDim.x + threadIdx.x;
  if (i < 1024) { arena[i] = rdw(spk, i, f); return; } i -= 1024;
  if (i < 128)  { arena[1024 + i] = rdw(c1, i, f); return; } i -= 128;
  if (i < 128)  { arena[1152 + i] = rdw(c3, i, f); return; } i -= 128;
  if (i < 256)  { arena[1280 + i] = rdw(b1, i, f); return; } i -= 256;
  if (i < 256)  { arena[1536 + i] = rdw(b2, i, f); return; } i -= 256;
  if (i < 256)  { arena[1792 + i] = rdw(b3, i, f); return; } i -= 256;
  if (i < 256)  { arena[2048 + i] = rdw(b4, i, f); return; } i -= 256;
  if (i < 128)  { arena[2304 + i] = rdw(bd1, i, f); return; } i -= 128;
  if (i < 64)   { arena[10624 + i] = rdw(bd2, i, f); return; } i -= 64;
  if (i < 64)   { arena[10688 + i] = rdw(wd3, i, f); return; } i -= 64;
  if (i < 1)    { arena[10752 + i] = rdw(bd3, i, f); return; } i -= 1;
  if (i < 8192) { int o = i >> 7, k = i & 127;          // wd2T[o,k] = wd2[k,o]
    arena[10880 + i] = rdw(wd2, k * 64 + o, f); }
}

// ---------------- vectorized convert (n multiple of 4) ----------------------
__global__ void cvt4(const void* __restrict__ in, u16* __restrict__ out, int n,
                     const int* __restrict__ flag){
  int i = (blockIdx.x * blockDim.x + threadIdx.x) * 4;
  if (i >= n) return;
  ushort4 o;
  if (*flag) {
    float4 v = *(const float4*)((const float*)in + i);
    o.x = f2b(v.x); o.y = f2b(v.y); o.z = f2b(v.z); o.w = f2b(v.w);
  } else {
    o = *(const ushort4*)((const u16*)in + i);
  }
  *(ushort4*)(out + i) = o;
}

// ---------------- weight packing: transpose B matrices to [NOUT, K] ----------
__global__ void pack_weights(const void* __restrict__ bases1, const void* __restrict__ root1,
                             const void* __restrict__ w2_rel, const void* __restrict__ w2_root,
                             const void* __restrict__ bases3, const void* __restrict__ root3,
                             const void* __restrict__ w4_rel, const void* __restrict__ w4_root,
                             const void* __restrict__ wd1,
                             u16* __restrict__ B1t, u16* __restrict__ B3t,
                             u16* __restrict__ B2t, u16* __restrict__ B4t,
                             u16* __restrict__ D1t, const int* __restrict__ flag)
{
  int f = *flag;
  int idx = blockIdx.x * blockDim.x + threadIdx.x;
  if (idx < 256*2304) { int o = idx / 2304, k = idx % 2304;
    B1t[idx] = (k < 2048) ? rdw(bases1, k*256 + o, f) : rdw(root1, (k-2048)*256 + o, f); return; }
  idx -= 256*2304;
  if (idx < 256*2304) { int o = idx / 2304, k = idx % 2304;
    B3t[idx] = (k < 2048) ? rdw(bases3, k*256 + o, f) : rdw(root3, (k-2048)*256 + o, f); return; }
  idx -= 256*2304;
  if (idx < 256*512) { int o = idx / 512, k = idx % 512;
    B2t[idx] = (k < 256) ? rdw(w2_rel, k*256 + o, f) : rdw(w2_root, (k-256)*256 + o, f); return; }
  idx -= 256*512;
  if (idx < 256*512) { int o = idx / 512, k = idx % 512;
    B4t[idx] = (k < 256) ? rdw(w4_rel, k*256 + o, f) : rdw(w4_root, (k-256)*256 + o, f); return; }
  idx -= 256*512;
  if (idx < 128*768) { int o = idx / 768, k = idx % 768;
    D1t[idx] = rdw(wd1, k*128 + o, f); }
}

// ---------------- x = encoding + spk_table[speaker] -------------------------
__global__ void build_x(const void* __restrict__ enc, const int* __restrict__ speaker,
                        const u16* __restrict__ spkA /* bf16 [4,256] */,
                        u16* __restrict__ X /* [N,256] */, int N,
                        const int* __restrict__ flag)
{
  int f = *flag;
  int idx = blockIdx.x * blockDim.x + threadIdx.x;
  if (idx >= N * 64) return;
  int n = idx >> 6, c = (idx & 63) * 4;
  int sp = speaker[n];
  ushort4 sv = *(const ushort4*)(spkA + (size_t)sp*256 + c);
  float e0, e1, e2, e3;
  if (f) {
    float4 ev = *(const float4*)((const float*)enc + (size_t)n*256 + c);
    e0 = ev.x; e1 = ev.y; e2 = ev.z; e3 = ev.w;
  } else {
    ushort4 ev = *(const ushort4*)((const u16*)enc + (size_t)n*256 + c);
    e0 = b2f(ev.x); e1 = b2f(ev.y); e2 = b2f(ev.z); e3 = b2f(ev.w);
  }
  ushort4 xv;
  xv.x = f2b(e0 + b2f(sv.x));
  xv.y = f2b(e1 + b2f(sv.y));
  xv.z = f2b(e2 + b2f(sv.z));
  xv.w = f2b(e3 + b2f(sv.w));
  *(ushort4*)(X + (size_t)n*256 + c) = xv;
}

// ---------------- dst-degree histogram ---------------------------------------
__global__ void edge_hist(const int* __restrict__ ei, int* cnt_dst, int E)
{
  int e = blockIdx.x * blockDim.x + threadIdx.x;
  if (e >= E) return;
  atomicAdd(&cnt_dst[ei[E + e]], 1);
}

// ---------------- 3-phase parallel exclusive scan ---------------------------
__global__ void scan_p1(const int* __restrict__ cnt, int* __restrict__ partial,
                        int* __restrict__ bsum, int N)
{
  __shared__ int s[256];
  int t = threadIdx.x;
  int g = blockIdx.x * 256 + t;
  int v = (g < N) ? cnt[g] : 0;
  s[t] = v; __syncthreads();
  #pragma unroll
  for (int off = 1; off < 256; off <<= 1) {
    int u = (t >= off) ? s[t - off] : 0;
    __syncthreads();
    s[t] += u;
    __syncthreads();
  }
  partial[g] = s[t];                       // inclusive
  if (t == 255) bsum[blockIdx.x] = s[255];
}

__global__ void scan_p2(int* __restrict__ bsum, int nb)
{
  __shared__ int s[1024];
  int t = threadIdx.x;
  int v = (t < nb) ? bsum[t] : 0;
  s[t] = v; __syncthreads();
  #pragma unroll
  for (int off = 1; off < 1024; off <<= 1) {
    int u = (t >= off) ? s[t - off] : 0;
    __syncthreads();
    s[t] += u;
    __syncthreads();
  }
  if (t < nb) bsum[t] = s[t] - v;          // exclusive
  if (t == nb - 1) bsum[nb] = s[t];        // total
}

__global__ void scan_p3(const int* __restrict__ cnt, const int* __restrict__ partial,
                        const int* __restrict__ bsum, int* __restrict__ basep, int N)
{
  int g = blockIdx.x * 256 + threadIdx.x;
  if (g < N) basep[g] = partial[g] - cnt[g] + bsum[blockIdx.x];
  if (g == 0) basep[N] = bsum[(N + 255) / 256];
}

// ---------------- scatter edges into dst-sorted order, packed ---------------
__global__ void edge_scatter(const int* __restrict__ ei, const int* __restrict__ et,
                             const int* __restrict__ est, const int* __restrict__ basep,
                             int* cursor, int* __restrict__ esorted, int E)
{
  int e = blockIdx.x * blockDim.x + threadIdx.x;
  if (e >= E) return;
  int d = ei[E + e];
  int pos = basep[d] + atomicAdd(&cursor[d], 1);
  esorted[pos] = ei[e] | (et[e] << 17) | (est[e] << 21);  // src<2^17, 4+4 bits rels
}

// ------- merged RGCN aggregation (conv1+conv3), in-wave rel counts ----------
__global__ __launch_bounds__(256) void rgcn_agg2(
    const int* __restrict__ esorted, const int* __restrict__ basep,
    const u16* __restrict__ X /* [N,256] */,
    const u16* __restrict__ comp1 /* bf16 [16,8] */,
    const u16* __restrict__ comp3 /* bf16 [16,8] */,
    u16* __restrict__ Mix1 /* [CR,2048] */,
    u16* __restrict__ Mix3 /* [CR,2048] */,
    int n0, int CR)
{
  __shared__ float sc1[128], sc3[128];
  if (threadIdx.x < 128) sc1[threadIdx.x] = b2f(comp1[threadIdx.x]);
  else sc3[threadIdx.x - 128] = b2f(comp3[threadIdx.x - 128]);
  __syncthreads();
  int nl = blockIdx.x * 4 + (threadIdx.x >> 6);
  if (nl >= CR) return;
  int n = n0 + nl;
  int lane = threadIdx.x & 63;
  int e0 = basep[n], e1 = basep[n + 1];
  // counting pass: lanes 0-15 count et==lane, lanes 16-31 count est==lane-16
  int myrel = lane & 15;
  int cnt = 0;
  for (int e = e0; e < e1; e++) {
    int rec = esorted[e];
    int r1 = (rec >> 17) & 15, r3 = (rec >> 21) & 15;
    if (lane < 16) cnt += (r1 == myrel);
    else if (lane < 32) cnt += (r3 == myrel);
  }
  float invv = 1.0f / (float)(cnt > 1 ? cnt : 1);
  // main pass
  float acc1[8][4] = {}, acc3[8][4] = {};
  for (int e = e0; e < e1; e++) {
    int rec = esorted[e];
    int src = rec & 0x1FFFF;
    int r1 = (rec >> 17) & 15, r3 = (rec >> 21) & 15;
    float iv1 = __shfl(invv, r1);
    float iv3 = __shfl(invv, 16 + r3);
    ushort4 xr = *(const ushort4*)(X + (size_t)src * 256 + lane * 4);
    float x0 = b2f(xr.x), x1 = b2f(xr.y), x2 = b2f(xr.z), x3 = b2f(xr.w);
    const float* c1p = sc1 + r1 * 8;
    const float* c3p = sc3 + r3 * 8;
    #pragma unroll
    for (int b = 0; b < 8; b++) {
      float w1 = c1p[b] * iv1;
      acc1[b][0] += w1 * x0; acc1[b][1] += w1 * x1;
      acc1[b][2] += w1 * x2; acc1[b][3] += w1 * x3;
      float w3 = c3p[b] * iv3;
      acc3[b][0] += w3 * x0; acc3[b][1] += w3 * x1;
      acc3[b][2] += w3 * x2; acc3[b][3] += w3 * x3;
    }
  }
  #pragma unroll
  for (int b = 0; b < 8; b++) {
    ushort4 o1, o3;
    o1.x = f2b(acc1[b][0]); o1.y = f2b(acc1[b][1]);
    o1.z = f2b(acc1[b][2]); o1.w = f2b(acc1[b][3]);
    o3.x = f2b(acc3[b][0]); o3.y = f2b(acc3[b][1]);
    o3.z = f2b(acc3[b][2]); o3.w = f2b(acc3[b][3]);
    *(ushort4*)(Mix1 + (size_t)nl * 2048 + b * 256 + lane * 4) = o1;
    *(ushort4*)(Mix3 + (size_t)nl * 2048 + b * 256 + lane * 4) = o3;
  }
}

// -------- GraphConv sum-aggregation: 16B/lane, 2 edges per wave-iter --------
__global__ __launch_bounds__(256) void gconv_agg(
    const int* __restrict__ esorted, const int* __restrict__ basep,
    const u16* __restrict__ Hin /* [N,256] */,
    u16* __restrict__ Agg /* [N,256] */, int N)
{
  int n = blockIdx.x * 4 + (threadIdx.x >> 6);
  if (n >= N) return;
  int lane = threadIdx.x & 63;
  int half = lane >> 5, l32 = lane & 31;
  float a[8] = {};
  int e0 = basep[n], e1 = basep[n + 1];
  for (int e = e0; e < e1; e += 2) {
    int ee = e + half;
    bool ok = ee < e1;
    int src = esorted[ok ? ee : e] & 0x1FFFF;
    short8 hv = *(const short8*)(Hin + (size_t)src * 256 + l32 * 8);
    if (ok) {
      #pragma unroll
      for (int j = 0; j < 8; j++) a[j] += b2f((u16)hv[j]);
    }
  }
  #pragma unroll
  for (int j = 0; j < 8; j++) a[j] += __shfl_xor(a[j], 32);
  if (half == 0) {
    short8 o;
    #pragma unroll
    for (int j = 0; j < 8; j++) o[j] = (short)f2b(a[j]);
    *(short8*)(Agg + (size_t)n * 256 + l32 * 8) = o;
  }
}

// ------------- multi-source bf16 MFMA GEMM, m97 structure -------------------
// 128x128 tile, 64x64 per wave, BK=64, global_load_lds(16B) staging.
// Fetch side XOR-swizzles the k-chunk (colA); LDS writes are linear lane-order
// (conflict-free); reads XOR back: logical chunk cb of row m lives at
// physical chunk cb^(m&7). m&7 == lm&7 for all fragment rows.
__global__ __launch_bounds__(256) void gemm_ms(
    const u16* __restrict__ A0, int lda0,
    const u16* __restrict__ A1, int lda1,
    const u16* __restrict__ A2, int lda2,
    int c1, int c2,
    const u16* __restrict__ Bt, /* [nout, K] */
    const u16* __restrict__ bias,
    u16* __restrict__ Cout, int ldc,
    int M, int K, int relu, int nout, int nx,
    const u16* __restrict__ A0d, const u16* __restrict__ Btd,
    const u16* __restrict__ biasd, u16* __restrict__ Coutd)
{
  constexpr int BK = 64;
  __shared__ u16 As[128 * BK];
  __shared__ u16 Bs[128 * BK];
  int bi = blockIdx.x;
  const u16* A0u = A0; const u16* Btu = Bt; const u16* biasu = bias;
  u16* Cu = Cout;
  if (bi >= nx) { bi -= nx; A0u = A0d; Btu = Btd; biasu = biasd; Cu = Coutd; }
  int nblk = (nout + 127) >> 7;           // 128-wide n-blocks
  int grpw = nblk << 3;
  int g = bi / grpw, r = bi % grpw;
  int bm = (g * 8 + (r & 7)) * 128;
  if (bm >= M) return;                    // uniform per block — safe
  int bn = (r >> 3) * 128;

  int tid = threadIdx.x;
  int wid = tid >> 6, lane = tid & 63;
  int wm = (wid & 1) * 64, wn = (wid >> 1) * 64;
  int r8 = lane >> 3;                     // row within 8-row staging group
  int colA = ((lane & 7) ^ r8) * 8;       // swizzled k-chunk this lane fetches
  int rloc = wid * 8 + r8;                // row within 32-row group
  int lm = lane & 15, quad = lane >> 4;

  f32x4 acc[4][4];
  #pragma unroll
  for (int i = 0; i < 4; i++)
    #pragma unroll
    for (int j = 0; j < 4; j++) acc[i][j] = (f32x4)0.0f;

  // clamped fetch rows (per-lane; LDS dest stays wave-uniform)
  int ga0 = bm + 0 * 32 + rloc; ga0 = ga0 < M ? ga0 : M - 1;
  int ga1 = bm + 1 * 32 + rloc; ga1 = ga1 < M ? ga1 : M - 1;
  int ga2 = bm + 2 * 32 + rloc; ga2 = ga2 < M ? ga2 : M - 1;
  int ga3 = bm + 3 * 32 + rloc; ga3 = ga3 < M ? ga3 : M - 1;
  int gb0 = bn + 0 * 32 + rloc; gb0 = gb0 < nout ? gb0 : nout - 1;
  int gb1 = bn + 1 * 32 + rloc; gb1 = gb1 < nout ? gb1 : nout - 1;
  int gb2 = bn + 2 * 32 + rloc; gb2 = gb2 < nout ? gb2 : nout - 1;
  int gb3 = bn + 3 * 32 + rloc; gb3 = gb3 < nout ? gb3 : nout - 1;

  for (int k0 = 0; k0 < K; k0 += BK) {
    const u16* srcp; int ldas, kO;        // wave-uniform (k0 uniform)
    if (k0 < c1)      { srcp = A0u; ldas = lda0; kO = k0; }
    else if (k0 < c2) { srcp = A1;  ldas = lda1; kO = k0 - c1; }
    else              { srcp = A2;  ldas = lda2; kO = k0 - c2; }
    const u16* abase = srcp + kO + colA;
    gload_lds16(abase + (size_t)ga0 * ldas, As + (0 * 32 + wid * 8) * BK);
    gload_lds16(abase + (size_t)ga1 * ldas, As + (1 * 32 + wid * 8) * BK);
    gload_lds16(abase + (size_t)ga2 * ldas, As + (2 * 32 + wid * 8) * BK);
    gload_lds16(abase + (size_t)ga3 * ldas, As + (3 * 32 + wid * 8) * BK);
    const u16* bbase = Btu + k0 + colA;
    gload_lds16(bbase + (size_t)gb0 * K, Bs + (0 * 32 + wid * 8) * BK);
    gload_lds16(bbase + (size_t)gb1 * K, Bs + (1 * 32 + wid * 8) * BK);
    gload_lds16(bbase + (size_t)gb2 * K, Bs + (2 * 32 + wid * 8) * BK);
    gload_lds16(bbase + (size_t)gb3 * K, Bs + (3 * 32 + wid * 8) * BK);
    __syncthreads();
    #pragma unroll
    for (int kk = 0; kk < BK; kk += 32) {
      int cb = (kk >> 3) + quad;
      int xo = ((cb ^ (lm & 7)) << 3);    // same for all fragment rows
      short8 af[4], bf[4];
      #pragma unroll
      for (int mi = 0; mi < 4; mi++)
        af[mi] = *(const short8*)(As + (wm + mi * 16 + lm) * BK + xo);
      #pragma unroll
      for (int ni = 0; ni < 4; ni++)
        bf[ni] = *(const short8*)(Bs + (wn + ni * 16 + lm) * BK + xo);
      #pragma unroll
      for (int mi = 0; mi < 4; mi++)
        #pragma unroll
        for (int ni = 0; ni < 4; ni++)
          acc[mi][ni] = __builtin_amdgcn_mfma_f32_16x16x32_bf16(
              af[mi], bf[ni], acc[mi][ni], 0, 0, 0);
    }
    __syncthreads();
  }
  #pragma unroll
  for (int ni = 0; ni < 4; ni++) {
    int gn = bn + wn + ni * 16 + lm;
    int gnb = gn < nout ? gn : nout - 1;
    float bv = b2f(biasu[gnb]);
    #pragma unroll
    for (int mi = 0; mi < 4; mi++) {
      int rbase = bm + wm + mi * 16 + quad * 4;
      #pragma unroll
      for (int rr = 0; rr < 4; rr++) {
        int gmr = rbase + rr;
        if (gmr < M && gn < nout) {
          float v = acc[mi][ni][rr] + bv;
          if (relu) v = fmaxf(v, 0.f);
          Cu[(size_t)gmr * ldc + gn] = f2b(v);
        }
      }
    }
  }
}

// ---------------- final dot: out[n] = sum_o h2m[n,o]*wd3[o] + bd3 -----------
__global__ __launch_bounds__(256) void mlp_tail2(
    const u16* __restrict__ h2m, const u16* __restrict__ wd3,
    const u16* __restrict__ bd3, void* __restrict__ outp, int N,
    const int* __restrict__ flag)
{
  int n = blockIdx.x * 4 + (threadIdx.x >> 6);
  if (n >= N) return;
  int lane = threadIdx.x & 63;
  float r = b2f(h2m[(size_t)n * 64 + lane]) * b2f(wd3[lane]);
  #pragma unroll
  for (int off = 32; off > 0; off >>= 1) r += __shfl_xor(r, off, 64);
  if (lane == 0) {
    float v = r + b2f(bd3[0]);
    if (*flag) ((float*)outp)[n] = v;
    else       ((u16*)outp)[n] = f2b(v);
  }
}

__global__ void sentinel(u16* out, int n, float code){
  int i = blockIdx.x * blockDim.x + threadIdx.x;
  if (i < n) out[i] = f2b(code);
}

extern "C" void kernel_launch(void* const* d_in, const int* in_sizes, int n_in,
                              void* d_out, int out_size, void* d_ws, size_t ws_size,
                              hipStream_t stream)
{
  const void* enc     = d_in[0];
  const int* speaker  = (const int*)d_in[1];
  const int* ei       = (const int*)d_in[2];
  const int* et       = (const int*)d_in[3];
  const int* est      = (const int*)d_in[4];
  const void* spk_tab = d_in[5];
  const void* comp1   = d_in[6];
  const void* bases1  = d_in[7];
  const void* root1   = d_in[8];
  const void* b1      = d_in[9];
  const void* w2_rel  = d_in[10];
  const void* b2      = d_in[11];
  const void* w2_root = d_in[12];
  const void* comp3   = d_in[13];
  const void* bases3  = d_in[14];
  const void* root3   = d_in[15];
  const void* b3      = d_in[16];
  const void* w4_rel  = d_in[17];
  const void* b4      = d_in[18];
  const void* w4_root = d_in[19];
  const void* wd1     = d_in[20];
  const void* bd1     = d_in[21];
  const void* wd2     = d_in[22];
  const void* bd2     = d_in[23];
  const void* wd3     = d_in[24];
  const void* bd3     = d_in[25];

  int N = in_sizes[1];     // 60000
  int E = in_sizes[3];     // 480000
  int nb = (N + 255) / 256;

  char* ws = (char*)d_ws;
  size_t off = 0;
  auto alloc = [&](size_t bytes) -> char* {
    char* p = ws + off; off = (off + bytes + 255) & ~(size_t)255; return p;
  };
  // ---- fixed pool (live across phases) ----
  u16* X    = (u16*)alloc((size_t)N * 256 * 2);   // x = enc+spk; later bf16 enc
  u16* hA   = (u16*)alloc((size_t)N * 256 * 2);   // conv1 rgcn out
  u16* hA3  = (u16*)alloc((size_t)N * 256 * 2);   // conv3 rgcn out
  u16* B1t  = (u16*)alloc((size_t)256 * 2304 * 2);
  u16* B3t  = (u16*)alloc((size_t)256 * 2304 * 2);
  u16* B2t  = (u16*)alloc((size_t)256 * 512 * 2);
  u16* B4t  = (u16*)alloc((size_t)256 * 512 * 2);
  u16* D1t  = (u16*)alloc((size_t)128 * 768 * 2);
  u16* arena = (u16*)alloc((size_t)20480 * 2);
  int* flag    = (int*)alloc(256);
  int* basep   = (int*)alloc((size_t)(N + 1) * 4);
  int* esorted = (int*)alloc((size_t)E * 4);

  // ---- phase-overlaid region R ----
  char* R = ws + off;
  size_t Rsize = (ws_size > off) ? (ws_size - off) : 0;

  int* cnt_dst = (int*)R;
  int* cursor  = (int*)(R + (size_t)N * 4);
  int* partial = (int*)(R + (size_t)2 * N * 4);
  int* bsum    = (int*)(R + (size_t)2 * N * 4 + (size_t)nb * 256 * 4);
  size_t zspan = (size_t)2 * N * 4;

  u16* AggB = (u16*)R;                            // phase 2
  u16* hB   = (u16*)(R + (size_t)N * 256 * 2);
  u16* hC   = (u16*)(R + (size_t)2 * N * 256 * 2);
  u16* h1m  = AggB;                               // [N,128]
  u16* h2m  = AggB + (size_t)N * 128;             // [N,64]
  size_t phase2_need = (size_t)3 * N * 256 * 2;

  long crl = (long)(Rsize / (4096 * 2));
  int chunk_rows = (int)((crl / 128) * 128);
  int Mpad = ((N + 127) / 128) * 128;
  if (chunk_rows > Mpad) chunk_rows = Mpad;

  size_t sort_need = (size_t)2 * N * 4 + (size_t)nb * 256 * 4 + 2048 * 4;
  if (chunk_rows < 128 || Rsize < phase2_need || Rsize < sort_need) {
    float code = 2000.0f + (float)(ws_size >> 20);
    sentinel<<<(out_size + 255) / 256, 256, 0, stream>>>((u16*)d_out, out_size, code);
    return;
  }
  u16* Mix1blk = (u16*)R;                         // phase 1
  u16* Mix3blk = Mix1blk + (size_t)chunk_rows * 2048;

  // arena layout (u16 offsets)
  u16* spkA   = arena + 0;
  u16* comp1A = arena + 1024;
  u16* comp3A = arena + 1152;
  u16* b1A    = arena + 1280;
  u16* b2A    = arena + 1536;
  u16* b3A    = arena + 1792;
  u16* b4A    = arena + 2048;
  u16* bd1A   = arena + 2304;
  u16* bd2A   = arena + 10624;
  u16* wd3A   = arena + 10688;
  u16* bd3A   = arena + 10752;
  u16* wd2T   = arena + 10880;   // [64,128]

  hipMemsetAsync(cnt_dst, 0, zspan, stream);

  detect_dtype<<<1, 256, 0, stream>>>((const u16*)enc, flag);
  cvt_small<<<75, 256, 0, stream>>>(spk_tab, comp1, comp3, b1, b2, b3, b4,
                                    bd1, wd2, bd2, wd3, bd3, arena, flag);

  int totpack = 256*2304*2 + 256*512*2 + 128*768;
  pack_weights<<<(totpack + 255) / 256, 256, 0, stream>>>(
      bases1, root1, w2_rel, w2_root, bases3, root3, w4_rel, w4_root, wd1,
      B1t, B3t, B2t, B4t, D1t, flag);
  build_x<<<(N * 64 + 255) / 256, 256, 0, stream>>>(enc, speaker, spkA, X, N, flag);
  edge_hist<<<(E + 255) / 256, 256, 0, stream>>>(ei, cnt_dst, E);
  scan_p1<<<nb, 256, 0, stream>>>(cnt_dst, partial, bsum, N);
  scan_p2<<<1, 1024, 0, stream>>>(bsum, nb);
  scan_p3<<<nb, 256, 0, stream>>>(cnt_dst, partial, bsum, basep, N);
  edge_scatter<<<(E + 255) / 256, 256, 0, stream>>>(ei, et, est, basep, cursor, esorted, E);

  int nb4 = (N + 3) / 4;
  const u16* nul = (const u16*)nullptr;
  auto nx_for = [](int M_, int nout_) {
    int mg = (M_ + 127) / 128;
    int nblk = (nout_ + 127) / 128;
    return ((mg + 7) / 8) * (nblk * 8);
  };

  // phase 1 — convs: merged aggregation + dual GEMM per chunk
  for (int n0 = 0; n0 < N; n0 += chunk_rows) {
    int CR = (N - n0 < chunk_rows) ? (N - n0) : chunk_rows;
    rgcn_agg2<<<(CR + 3) / 4, 256, 0, stream>>>(esorted, basep, X, comp1A, comp3A,
                                                Mix1blk, Mix3blk, n0, CR);
    int nx = nx_for(CR, 256);
    gemm_ms<<<2 * nx, 256, 0, stream>>>(
        Mix1blk, 2048, X + (size_t)n0 * 256, 256, nul, 0, 2048, 2304,
        B1t, b1A, hA + (size_t)n0 * 256, 256, CR, 2304, 0, 256, nx,
        Mix3blk, B3t, b3A, hA3 + (size_t)n0 * 256);
  }
  // phase 2 — gconv2: agg(h1_rgcn) -> [agg|h] @ [w2_rel;w2_root] -> hB
  int nxN = nx_for(N, 256);
  gconv_agg<<<nb4, 256, 0, stream>>>(esorted, basep, hA, AggB, N);
  gemm_ms<<<nxN, 256, 0, stream>>>(
      AggB, 256, hA, 256, nul, 0, 256, 512,
      B2t, b2A, hB, 256, N, 512, 0, 256, nxN, nul, nul, nul, (u16*)nullptr);
  // gconv4
  gconv_agg<<<nb4, 256, 0, stream>>>(esorted, basep, hA3, AggB, N);
  cvt4<<<(N * 64 + 255) / 256, 256, 0, stream>>>(enc, X, N * 256, flag);  // X dead -> bf16 enc
  gemm_ms<<<nxN, 256, 0, stream>>>(
      AggB, 256, hA3, 256, nul, 0, 256, 512,
      B4t, b4A, hC, 256, N, 512, 0, 256, nxN, nul, nul, nul, (u16*)nullptr);

  // MLP layer 1: [enc|h1|h2] @ wd1 (+bd1, relu) -> h1m [N,128]
  int nx1 = nx_for(N, 128);
  gemm_ms<<<nx1, 256, 0, stream>>>(
      X, 256, hB, 256, hC, 256, 256, 512,
      D1t, bd1A, h1m, 128, N, 768, 1, 128, nx1, nul, nul, nul, (u16*)nullptr);
  // MLP layer 2: h1m @ wd2 (+bd2, relu) -> h2m [N,64]
  int nx2 = nx_for(N, 64);
  gemm_ms<<<nx2, 256, 0, stream>>>(
      h1m, 128, nul, 0, nul, 0, 128, 128,
      wd2T, bd2A, h2m, 64, N, 128, 1, 64, nx2, nul, nul, nul, (u16*)nullptr);
  // MLP layer 3
  mlp_tail2<<<nb4, 256, 0, stream>>>(h2m, wd3A, bd3A, d_out, N, flag);
}

// Round 12
// 778.128 us; speedup vs baseline: 42.1218x; 1.0188x over previous
//
#include <hip/hip_runtime.h>
#include <stdint.h>

// PreEncodedGCN on MI355X — round 12.
// vs r11: (1) equal grid-friendly conv chunks (8 block-rounds vs 10);
// (2) rgcn_agg2 inner loop on float2 (v_pk_fma_f32, ~48 vs 80 VALU/edge);
// (3) gconv aggregation for both convs merged into one edge pass;
// (4) gemm_ms grows A1d -> gconv2+gconv4 run as one dual GEMM launch.

typedef unsigned short u16;
typedef __attribute__((ext_vector_type(2))) float f32x2;
typedef __attribute__((ext_vector_type(4))) float f32x4;
typedef __attribute__((ext_vector_type(8))) short short8;

__device__ __forceinline__ float b2f(u16 u){
  union { uint32_t i; float f; } v; v.i = ((uint32_t)u) << 16; return v.f;
}
__device__ __forceinline__ u16 f2b(float f){
  union { float f; uint32_t i; } v; v.f = f;
  uint32_t u = v.i;
  return (u16)((u + 0x7FFFu + ((u >> 16) & 1u)) >> 16);
}
__device__ __forceinline__ u16 rdw(const void* p, size_t i, int f32){
  return f32 ? f2b(((const float*)p)[i]) : ((const u16*)p)[i];
}
__device__ __forceinline__ void gload_lds16(const u16* gp, u16* lp){
  __builtin_amdgcn_global_load_lds(
      (const __attribute__((address_space(1))) uint32_t*)(uintptr_t)gp,
      (__attribute__((address_space(3))) uint32_t*)lp, 16, 0, 0);
}

// ---------------- dtype detector: 1 = fp32, 0 = bf16 ------------------------
__global__ void detect_dtype(const u16* enc16, int* flag){
  __shared__ int cnt;
  if (threadIdx.x == 0) cnt = 0;
  __syncthreads();
  unsigned u = enc16[threadIdx.x * 2];
  int e = (u >> 7) & 0xFF;
  if (e >= 100 && e <= 140) atomicAdd(&cnt, 1);
  __syncthreads();
  if (threadIdx.x == 0) flag[0] = (cnt < 128) ? 1 : 0;
}

// ---------------- batched small-weight conversion ---------------------------
__global__ void cvt_small(const void* spk, const void* c1, const void* c3,
                          const void* b1, const void* b2, const void* b3,
                          const void* b4, const void* bd1, const void* wd2,
                          const void* bd2, const void* wd3, const void* bd3,
                          u16* __restrict__ arena, const int* __restrict__ flag)
{
  int f = *flag;
  int i = blockIdx.x * blockDim.x + threadIdx.x;
  if (i < 1024) { arena[i] = rdw(spk, i, f); return; } i -= 1024;
  if (i < 128)  { arena[1024 + i] = rdw(c1, i, f); return; } i -= 128;
  if (i < 128)  { arena[1152 + i] = rdw(c3, i, f); return; } i -= 128;
  if (i < 256)  { arena[1280 + i] = rdw(b1, i, f); return; } i -= 256;
  if (i < 256)  { arena[1536 + i] = rdw(b2, i, f); return; } i -= 256;
  if (i < 256)  { arena[1792 + i] = rdw(b3, i, f); return; } i -= 256;
  if (i < 256)  { arena[2048 + i] = rdw(b4, i, f); return; } i -= 256;
  if (i < 128)  { arena[2304 + i] = rdw(bd1, i, f); return; } i -= 128;
  if (i < 64)   { arena[10624 + i] = rdw(bd2, i, f); return; } i -= 64;
  if (i < 64)   { arena[10688 + i] = rdw(wd3, i, f); return; } i -= 64;
  if (i < 1)    { arena[10752 + i] = rdw(bd3, i, f); return; } i -= 1;
  if (i < 8192) { int o = i >> 7, k = i & 127;          // wd2T[o,k] = wd2[k,o]
    arena[10880 + i] = rdw(wd2, k * 64 + o, f); }
}

// ---------------- vectorized convert (n multiple of 4) ----------------------
__global__ void cvt4(const void* __restrict__ in, u16* __restrict__ out, int n,
                     const int* __restrict__ flag){
  int i = (blockIdx.x * blockDim.x + threadIdx.x) * 4;
  if (i >= n) return;
  ushort4 o;
  if (*flag) {
    float4 v = *(const float4*)((const float*)in + i);
    o.x = f2b(v.x); o.y = f2b(v.y); o.z = f2b(v.z); o.w = f2b(v.w);
  } else {
    o = *(const ushort4*)((const u16*)in + i);
  }
  *(ushort4*)(out + i) = o;
}

// ---------------- weight packing: transpose B matrices to [NOUT, K] ----------
__global__ void pack_weights(const void* __restrict__ bases1, const void* __restrict__ root1,
                             const void* __restrict__ w2_rel, const void* __restrict__ w2_root,
                             const void* __restrict__ bases3, const void* __restrict__ root3,
                             const void* __restrict__ w4_rel, const void* __restrict__ w4_root,
                             const void* __restrict__ wd1,
                             u16* __restrict__ B1t, u16* __restrict__ B3t,
                             u16* __restrict__ B2t, u16* __restrict__ B4t,
                             u16* __restrict__ D1t, const int* __restrict__ flag)
{
  int f = *flag;
  int idx = blockIdx.x * blockDim.x + threadIdx.x;
  if (idx < 256*2304) { int o = idx / 2304, k = idx % 2304;
    B1t[idx] = (k < 2048) ? rdw(bases1, k*256 + o, f) : rdw(root1, (k-2048)*256 + o, f); return; }
  idx -= 256*2304;
  if (idx < 256*2304) { int o = idx / 2304, k = idx % 2304;
    B3t[idx] = (k < 2048) ? rdw(bases3, k*256 + o, f) : rdw(root3, (k-2048)*256 + o, f); return; }
  idx -= 256*2304;
  if (idx < 256*512) { int o = idx / 512, k = idx % 512;
    B2t[idx] = (k < 256) ? rdw(w2_rel, k*256 + o, f) : rdw(w2_root, (k-256)*256 + o, f); return; }
  idx -= 256*512;
  if (idx < 256*512) { int o = idx / 512, k = idx % 512;
    B4t[idx] = (k < 256) ? rdw(w4_rel, k*256 + o, f) : rdw(w4_root, (k-256)*256 + o, f); return; }
  idx -= 256*512;
  if (idx < 128*768) { int o = idx / 768, k = idx % 768;
    D1t[idx] = rdw(wd1, k*128 + o, f); }
}

// ---------------- x = encoding + spk_table[speaker] -------------------------
__global__ void build_x(const void* __restrict__ enc, const int* __restrict__ speaker,
                        const u16* __restrict__ spkA /* bf16 [4,256] */,
                        u16* __restrict__ X /* [N,256] */, int N,
                        const int* __restrict__ flag)
{
  int f = *flag;
  int idx = blockIdx.x * blockDim.x + threadIdx.x;
  if (idx >= N * 64) return;
  int n = idx >> 6, c = (idx & 63) * 4;
  int sp = speaker[n];
  ushort4 sv = *(const ushort4*)(spkA + (size_t)sp*256 + c);
  float e0, e1, e2, e3;
  if (f) {
    float4 ev = *(const float4*)((const float*)enc + (size_t)n*256 + c);
    e0 = ev.x; e1 = ev.y; e2 = ev.z; e3 = ev.w;
  } else {
    ushort4 ev = *(const ushort4*)((const u16*)enc + (size_t)n*256 + c);
    e0 = b2f(ev.x); e1 = b2f(ev.y); e2 = b2f(ev.z); e3 = b2f(ev.w);
  }
  ushort4 xv;
  xv.x = f2b(e0 + b2f(sv.x));
  xv.y = f2b(e1 + b2f(sv.y));
  xv.z = f2b(e2 + b2f(sv.z));
  xv.w = f2b(e3 + b2f(sv.w));
  *(ushort4*)(X + (size_t)n*256 + c) = xv;
}

// ---------------- dst-degree histogram ---------------------------------------
__global__ void edge_hist(const int* __restrict__ ei, int* cnt_dst, int E)
{
  int e = blockIdx.x * blockDim.x + threadIdx.x;
  if (e >= E) return;
  atomicAdd(&cnt_dst[ei[E + e]], 1);
}

// ---------------- 3-phase parallel exclusive scan ---------------------------
__global__ void scan_p1(const int* __restrict__ cnt, int* __restrict__ partial,
                        int* __restrict__ bsum, int N)
{
  __shared__ int s[256];
  int t = threadIdx.x;
  int g = blockIdx.x * 256 + t;
  int v = (g < N) ? cnt[g] : 0;
  s[t] = v; __syncthreads();
  #pragma unroll
  for (int off = 1; off < 256; off <<= 1) {
    int u = (t >= off) ? s[t - off] : 0;
    __syncthreads();
    s[t] += u;
    __syncthreads();
  }
  partial[g] = s[t];                       // inclusive
  if (t == 255) bsum[blockIdx.x] = s[255];
}

__global__ void scan_p2(int* __restrict__ bsum, int nb)
{
  __shared__ int s[1024];
  int t = threadIdx.x;
  int v = (t < nb) ? bsum[t] : 0;
  s[t] = v; __syncthreads();
  #pragma unroll
  for (int off = 1; off < 1024; off <<= 1) {
    int u = (t >= off) ? s[t - off] : 0;
    __syncthreads();
    s[t] += u;
    __syncthreads();
  }
  if (t < nb) bsum[t] = s[t] - v;          // exclusive
  if (t == nb - 1) bsum[nb] = s[t];        // total
}

__global__ void scan_p3(const int* __restrict__ cnt, const int* __restrict__ partial,
                        const int* __restrict__ bsum, int* __restrict__ basep, int N)
{
  int g = blockIdx.x * 256 + threadIdx.x;
  if (g < N) basep[g] = partial[g] - cnt[g] + bsum[blockIdx.x];
  if (g == 0) basep[N] = bsum[(N + 255) / 256];
}

// ---------------- scatter edges into dst-sorted order, packed ---------------
__global__ void edge_scatter(const int* __restrict__ ei, const int* __restrict__ et,
                             const int* __restrict__ est, const int* __restrict__ basep,
                             int* cursor, int* __restrict__ esorted, int E)
{
  int e = blockIdx.x * blockDim.x + threadIdx.x;
  if (e >= E) return;
  int d = ei[E + e];
  int pos = basep[d] + atomicAdd(&cursor[d], 1);
  esorted[pos] = ei[e] | (et[e] << 17) | (est[e] << 21);  // src<2^17, 4+4 bits rels
}

// ------- merged RGCN aggregation (conv1+conv3), packed fp32 math ------------
__global__ __launch_bounds__(256) void rgcn_agg2(
    const int* __restrict__ esorted, const int* __restrict__ basep,
    const u16* __restrict__ X /* [N,256] */,
    const u16* __restrict__ comp1 /* bf16 [16,8] */,
    const u16* __restrict__ comp3 /* bf16 [16,8] */,
    u16* __restrict__ Mix1 /* [CR,2048] */,
    u16* __restrict__ Mix3 /* [CR,2048] */,
    int n0, int CR)
{
  __shared__ float sc1[128], sc3[128];
  if (threadIdx.x < 128) sc1[threadIdx.x] = b2f(comp1[threadIdx.x]);
  else sc3[threadIdx.x - 128] = b2f(comp3[threadIdx.x - 128]);
  __syncthreads();
  int nl = blockIdx.x * 4 + (threadIdx.x >> 6);
  if (nl >= CR) return;
  int n = n0 + nl;
  int lane = threadIdx.x & 63;
  int e0 = basep[n], e1 = basep[n + 1];
  // counting pass: lanes 0-15 count et==lane, lanes 16-31 count est==lane-16
  int myrel = lane & 15;
  int cnt = 0;
  for (int e = e0; e < e1; e++) {
    int rec = esorted[e];
    int r1 = (rec >> 17) & 15, r3 = (rec >> 21) & 15;
    if (lane < 16) cnt += (r1 == myrel);
    else if (lane < 32) cnt += (r3 == myrel);
  }
  float invv = 1.0f / (float)(cnt > 1 ? cnt : 1);
  // main pass (float2 -> v_pk_fma_f32)
  f32x2 acc1[8][2] = {}, acc3[8][2] = {};
  for (int e = e0; e < e1; e++) {
    int rec = esorted[e];
    int src = rec & 0x1FFFF;
    int r1 = (rec >> 17) & 15, r3 = (rec >> 21) & 15;
    float iv1 = __shfl(invv, r1);
    float iv3 = __shfl(invv, 16 + r3);
    ushort4 xr = *(const ushort4*)(X + (size_t)src * 256 + lane * 4);
    f32x2 xlo, xhi;
    xlo[0] = b2f(xr.x); xlo[1] = b2f(xr.y);
    xhi[0] = b2f(xr.z); xhi[1] = b2f(xr.w);
    const float* c1p = sc1 + r1 * 8;
    const float* c3p = sc3 + r3 * 8;
    #pragma unroll
    for (int b = 0; b < 8; b++) {
      float w1s = c1p[b] * iv1;
      f32x2 w1 = {w1s, w1s};
      acc1[b][0] += w1 * xlo; acc1[b][1] += w1 * xhi;
      float w3s = c3p[b] * iv3;
      f32x2 w3 = {w3s, w3s};
      acc3[b][0] += w3 * xlo; acc3[b][1] += w3 * xhi;
    }
  }
  #pragma unroll
  for (int b = 0; b < 8; b++) {
    ushort4 o1, o3;
    o1.x = f2b(acc1[b][0][0]); o1.y = f2b(acc1[b][0][1]);
    o1.z = f2b(acc1[b][1][0]); o1.w = f2b(acc1[b][1][1]);
    o3.x = f2b(acc3[b][0][0]); o3.y = f2b(acc3[b][0][1]);
    o3.z = f2b(acc3[b][1][0]); o3.w = f2b(acc3[b][1][1]);
    *(ushort4*)(Mix1 + (size_t)nl * 2048 + b * 256 + lane * 4) = o1;
    *(ushort4*)(Mix3 + (size_t)nl * 2048 + b * 256 + lane * 4) = o3;
  }
}

// -------- merged GraphConv sum-aggregation (both convs, one edge pass) ------
__global__ __launch_bounds__(256) void gconv_agg2(
    const int* __restrict__ esorted, const int* __restrict__ basep,
    const u16* __restrict__ HinA /* [N,256] */,
    const u16* __restrict__ HinB /* [N,256] */,
    u16* __restrict__ AggA /* [N,256] */,
    u16* __restrict__ AggB /* [N,256] */, int N)
{
  int n = blockIdx.x * 4 + (threadIdx.x >> 6);
  if (n >= N) return;
  int lane = threadIdx.x & 63;
  int half = lane >> 5, l32 = lane & 31;
  float a[8] = {}, b[8] = {};
  int e0 = basep[n], e1 = basep[n + 1];
  for (int e = e0; e < e1; e += 2) {
    int ee = e + half;
    bool ok = ee < e1;
    int src = esorted[ok ? ee : e] & 0x1FFFF;
    short8 hv  = *(const short8*)(HinA + (size_t)src * 256 + l32 * 8);
    short8 hv3 = *(const short8*)(HinB + (size_t)src * 256 + l32 * 8);
    if (ok) {
      #pragma unroll
      for (int j = 0; j < 8; j++) { a[j] += b2f((u16)hv[j]); b[j] += b2f((u16)hv3[j]); }
    }
  }
  #pragma unroll
  for (int j = 0; j < 8; j++) {
    a[j] += __shfl_xor(a[j], 32);
    b[j] += __shfl_xor(b[j], 32);
  }
  if (half == 0) {
    short8 oa, ob;
    #pragma unroll
    for (int j = 0; j < 8; j++) { oa[j] = (short)f2b(a[j]); ob[j] = (short)f2b(b[j]); }
    *(short8*)(AggA + (size_t)n * 256 + l32 * 8) = oa;
    *(short8*)(AggB + (size_t)n * 256 + l32 * 8) = ob;
  }
}

// ------------- multi-source bf16 MFMA GEMM, m97 structure -------------------
// 128x128 tile, 64x64/wave, BK=64, global_load_lds(16B), XOR-swizzled fetch.
// Dual: blocks >= nx use the d-set (A0d/A1d/Btd/biasd/Coutd).
__global__ __launch_bounds__(256) void gemm_ms(
    const u16* __restrict__ A0, int lda0,
    const u16* __restrict__ A1, int lda1,
    const u16* __restrict__ A2, int lda2,
    int c1, int c2,
    const u16* __restrict__ Bt, /* [nout, K] */
    const u16* __restrict__ bias,
    u16* __restrict__ Cout, int ldc,
    int M, int K, int relu, int nout, int nx,
    const u16* __restrict__ A0d, const u16* __restrict__ A1d,
    const u16* __restrict__ Btd,
    const u16* __restrict__ biasd, u16* __restrict__ Coutd)
{
  constexpr int BK = 64;
  __shared__ u16 As[128 * BK];
  __shared__ u16 Bs[128 * BK];
  int bi = blockIdx.x;
  const u16* A0u = A0; const u16* A1u = A1;
  const u16* Btu = Bt; const u16* biasu = bias;
  u16* Cu = Cout;
  if (bi >= nx) { bi -= nx; A0u = A0d; A1u = A1d; Btu = Btd; biasu = biasd; Cu = Coutd; }
  int nblk = (nout + 127) >> 7;           // 128-wide n-blocks
  int grpw = nblk << 3;
  int g = bi / grpw, r = bi % grpw;
  int bm = (g * 8 + (r & 7)) * 128;
  if (bm >= M) return;                    // uniform per block — safe
  int bn = (r >> 3) * 128;

  int tid = threadIdx.x;
  int wid = tid >> 6, lane = tid & 63;
  int wm = (wid & 1) * 64, wn = (wid >> 1) * 64;
  int r8 = lane >> 3;                     // row within 8-row staging group
  int colA = ((lane & 7) ^ r8) * 8;       // swizzled k-chunk this lane fetches
  int rloc = wid * 8 + r8;                // row within 32-row group
  int lm = lane & 15, quad = lane >> 4;

  f32x4 acc[4][4];
  #pragma unroll
  for (int i = 0; i < 4; i++)
    #pragma unroll
    for (int j = 0; j < 4; j++) acc[i][j] = (f32x4)0.0f;

  int ga0 = bm + 0 * 32 + rloc; ga0 = ga0 < M ? ga0 : M - 1;
  int ga1 = bm + 1 * 32 + rloc; ga1 = ga1 < M ? ga1 : M - 1;
  int ga2 = bm + 2 * 32 + rloc; ga2 = ga2 < M ? ga2 : M - 1;
  int ga3 = bm + 3 * 32 + rloc; ga3 = ga3 < M ? ga3 : M - 1;
  int gb0 = bn + 0 * 32 + rloc; gb0 = gb0 < nout ? gb0 : nout - 1;
  int gb1 = bn + 1 * 32 + rloc; gb1 = gb1 < nout ? gb1 : nout - 1;
  int gb2 = bn + 2 * 32 + rloc; gb2 = gb2 < nout ? gb2 : nout - 1;
  int gb3 = bn + 3 * 32 + rloc; gb3 = gb3 < nout ? gb3 : nout - 1;

  for (int k0 = 0; k0 < K; k0 += BK) {
    const u16* srcp; int ldas, kO;        // wave-uniform (k0 uniform)
    if (k0 < c1)      { srcp = A0u; ldas = lda0; kO = k0; }
    else if (k0 < c2) { srcp = A1u; ldas = lda1; kO = k0 - c1; }
    else              { srcp = A2;  ldas = lda2; kO = k0 - c2; }
    const u16* abase = srcp + kO + colA;
    gload_lds16(abase + (size_t)ga0 * ldas, As + (0 * 32 + wid * 8) * BK);
    gload_lds16(abase + (size_t)ga1 * ldas, As + (1 * 32 + wid * 8) * BK);
    gload_lds16(abase + (size_t)ga2 * ldas, As + (2 * 32 + wid * 8) * BK);
    gload_lds16(abase + (size_t)ga3 * ldas, As + (3 * 32 + wid * 8) * BK);
    const u16* bbase = Btu + k0 + colA;
    gload_lds16(bbase + (size_t)gb0 * K, Bs + (0 * 32 + wid * 8) * BK);
    gload_lds16(bbase + (size_t)gb1 * K, Bs + (1 * 32 + wid * 8) * BK);
    gload_lds16(bbase + (size_t)gb2 * K, Bs + (2 * 32 + wid * 8) * BK);
    gload_lds16(bbase + (size_t)gb3 * K, Bs + (3 * 32 + wid * 8) * BK);
    __syncthreads();
    #pragma unroll
    for (int kk = 0; kk < BK; kk += 32) {
      int cb = (kk >> 3) + quad;
      int xo = ((cb ^ (lm & 7)) << 3);    // same for all fragment rows
      short8 af[4], bf[4];
      #pragma unroll
      for (int mi = 0; mi < 4; mi++)
        af[mi] = *(const short8*)(As + (wm + mi * 16 + lm) * BK + xo);
      #pragma unroll
      for (int ni = 0; ni < 4; ni++)
        bf[ni] = *(const short8*)(Bs + (wn + ni * 16 + lm) * BK + xo);
      #pragma unroll
      for (int mi = 0; mi < 4; mi++)
        #pragma unroll
        for (int ni = 0; ni < 4; ni++)
          acc[mi][ni] = __builtin_amdgcn_mfma_f32_16x16x32_bf16(
              af[mi], bf[ni], acc[mi][ni], 0, 0, 0);
    }
    __syncthreads();
  }
  #pragma unroll
  for (int ni = 0; ni < 4; ni++) {
    int gn = bn + wn + ni * 16 + lm;
    int gnb = gn < nout ? gn : nout - 1;
    float bv = b2f(biasu[gnb]);
    #pragma unroll
    for (int mi = 0; mi < 4; mi++) {
      int rbase = bm + wm + mi * 16 + quad * 4;
      #pragma unroll
      for (int rr = 0; rr < 4; rr++) {
        int gmr = rbase + rr;
        if (gmr < M && gn < nout) {
          float v = acc[mi][ni][rr] + bv;
          if (relu) v = fmaxf(v, 0.f);
          Cu[(size_t)gmr * ldc + gn] = f2b(v);
        }
      }
    }
  }
}

// ---------------- final dot: out[n] = sum_o h2m[n,o]*wd3[o] + bd3 -----------
__global__ __launch_bounds__(256) void mlp_tail2(
    const u16* __restrict__ h2m, const u16* __restrict__ wd3,
    const u16* __restrict__ bd3, void* __restrict__ outp, int N,
    const int* __restrict__ flag)
{
  int n = blockIdx.x * 4 + (threadIdx.x >> 6);
  if (n >= N) return;
  int lane = threadIdx.x & 63;
  float r = b2f(h2m[(size_t)n * 64 + lane]) * b2f(wd3[lane]);
  #pragma unroll
  for (int off = 32; off > 0; off >>= 1) r += __shfl_xor(r, off, 64);
  if (lane == 0) {
    float v = r + b2f(bd3[0]);
    if (*flag) ((float*)outp)[n] = v;
    else       ((u16*)outp)[n] = f2b(v);
  }
}

__global__ void sentinel(u16* out, int n, float code){
  int i = blockIdx.x * blockDim.x + threadIdx.x;
  if (i < n) out[i] = f2b(code);
}

extern "C" void kernel_launch(void* const* d_in, const int* in_sizes, int n_in,
                              void* d_out, int out_size, void* d_ws, size_t ws_size,
                              hipStream_t stream)
{
  const void* enc     = d_in[0];
  const int* speaker  = (const int*)d_in[1];
  const int* ei       = (const int*)d_in[2];
  const int* et       = (const int*)d_in[3];
  const int* est      = (const int*)d_in[4];
  const void* spk_tab = d_in[5];
  const void* comp1   = d_in[6];
  const void* bases1  = d_in[7];
  const void* root1   = d_in[8];
  const void* b1      = d_in[9];
  const void* w2_rel  = d_in[10];
  const void* b2      = d_in[11];
  const void* w2_root = d_in[12];
  const void* comp3   = d_in[13];
  const void* bases3  = d_in[14];
  const void* root3   = d_in[15];
  const void* b3      = d_in[16];
  const void* w4_rel  = d_in[17];
  const void* b4      = d_in[18];
  const void* w4_root = d_in[19];
  const void* wd1     = d_in[20];
  const void* bd1     = d_in[21];
  const void* wd2     = d_in[22];
  const void* bd2     = d_in[23];
  const void* wd3     = d_in[24];
  const void* bd3     = d_in[25];

  int N = in_sizes[1];     // 60000
  int E = in_sizes[3];     // 480000
  int nb = (N + 255) / 256;

  char* ws = (char*)d_ws;
  size_t off = 0;
  auto alloc = [&](size_t bytes) -> char* {
    char* p = ws + off; off = (off + bytes + 255) & ~(size_t)255; return p;
  };
  // ---- fixed pool (live across phases) ----
  u16* X    = (u16*)alloc((size_t)N * 256 * 2);   // x = enc+spk; later bf16 enc
  u16* hA   = (u16*)alloc((size_t)N * 256 * 2);   // conv1 rgcn out
  u16* hA3  = (u16*)alloc((size_t)N * 256 * 2);   // conv3 rgcn out
  u16* B1t  = (u16*)alloc((size_t)256 * 2304 * 2);
  u16* B3t  = (u16*)alloc((size_t)256 * 2304 * 2);
  u16* B2t  = (u16*)alloc((size_t)256 * 512 * 2);
  u16* B4t  = (u16*)alloc((size_t)256 * 512 * 2);
  u16* D1t  = (u16*)alloc((size_t)128 * 768 * 2);
  u16* arena = (u16*)alloc((size_t)20480 * 2);
  int* flag    = (int*)alloc(256);
  int* basep   = (int*)alloc((size_t)(N + 1) * 4);
  int* esorted = (int*)alloc((size_t)E * 4);

  // ---- phase-overlaid region R ----
  char* R = ws + off;
  size_t Rsize = (ws_size > off) ? (ws_size - off) : 0;

  int* cnt_dst = (int*)R;
  int* cursor  = (int*)(R + (size_t)N * 4);
  int* partial = (int*)(R + (size_t)2 * N * 4);
  int* bsum    = (int*)(R + (size_t)2 * N * 4 + (size_t)nb * 256 * 4);
  size_t zspan = (size_t)2 * N * 4;

  u16* AggA = (u16*)R;                            // phase 2
  u16* hB   = (u16*)(R + (size_t)N * 256 * 2);
  u16* hC   = (u16*)(R + (size_t)2 * N * 256 * 2);
  u16* AggC = (u16*)(R + (size_t)3 * N * 256 * 2);
  u16* h1m  = AggA;                               // [N,128] (Aggs dead by MLP)
  u16* h2m  = AggA + (size_t)N * 128;             // [N,64]
  size_t phase2_need = (size_t)4 * N * 256 * 2;

  long crl = (long)(Rsize / (4096 * 2));
  int chunk_max = (int)((crl / 128) * 128);
  int Mpad = ((N + 127) / 128) * 128;
  if (chunk_max > Mpad) chunk_max = Mpad;

  size_t sort_need = (size_t)2 * N * 4 + (size_t)nb * 256 * 4 + 2048 * 4;
  if (chunk_max < 128 || Rsize < phase2_need || Rsize < sort_need) {
    float code = 2000.0f + (float)(ws_size >> 20);
    sentinel<<<(out_size + 255) / 256, 256, 0, stream>>>((u16*)d_out, out_size, code);
    return;
  }
  // equal, grid-friendly chunks
  int nchunks = (Mpad + chunk_max - 1) / chunk_max;
  int chunk_rows = (((N + nchunks - 1) / nchunks + 127) / 128) * 128;
  u16* Mix1blk = (u16*)R;                         // phase 1
  u16* Mix3blk = Mix1blk + (size_t)chunk_rows * 2048;

  // arena layout (u16 offsets)
  u16* spkA   = arena + 0;
  u16* comp1A = arena + 1024;
  u16* comp3A = arena + 1152;
  u16* b1A    = arena + 1280;
  u16* b2A    = arena + 1536;
  u16* b3A    = arena + 1792;
  u16* b4A    = arena + 2048;
  u16* bd1A   = arena + 2304;
  u16* bd2A   = arena + 10624;
  u16* wd3A   = arena + 10688;
  u16* bd3A   = arena + 10752;
  u16* wd2T   = arena + 10880;   // [64,128]

  hipMemsetAsync(cnt_dst, 0, zspan, stream);

  detect_dtype<<<1, 256, 0, stream>>>((const u16*)enc, flag);
  cvt_small<<<75, 256, 0, stream>>>(spk_tab, comp1, comp3, b1, b2, b3, b4,
                                    bd1, wd2, bd2, wd3, bd3, arena, flag);

  int totpack = 256*2304*2 + 256*512*2 + 128*768;
  pack_weights<<<(totpack + 255) / 256, 256, 0, stream>>>(
      bases1, root1, w2_rel, w2_root, bases3, root3, w4_rel, w4_root, wd1,
      B1t, B3t, B2t, B4t, D1t, flag);
  build_x<<<(N * 64 + 255) / 256, 256, 0, stream>>>(enc, speaker, spkA, X, N, flag);
  edge_hist<<<(E + 255) / 256, 256, 0, stream>>>(ei, cnt_dst, E);
  scan_p1<<<nb, 256, 0, stream>>>(cnt_dst, partial, bsum, N);
  scan_p2<<<1, 1024, 0, stream>>>(bsum, nb);
  scan_p3<<<nb, 256, 0, stream>>>(cnt_dst, partial, bsum, basep, N);
  edge_scatter<<<(E + 255) / 256, 256, 0, stream>>>(ei, et, est, basep, cursor, esorted, E);

  int nb4 = (N + 3) / 4;
  const u16* nul = (const u16*)nullptr;
  auto nx_for = [](int M_, int nout_) {
    int mg = (M_ + 127) / 128;
    int nblk = (nout_ + 127) / 128;
    return ((mg + 7) / 8) * (nblk * 8);
  };

  // phase 1 — convs: merged aggregation + dual GEMM per chunk
  for (int n0 = 0; n0 < N; n0 += chunk_rows) {
    int CR = (N - n0 < chunk_rows) ? (N - n0) : chunk_rows;
    rgcn_agg2<<<(CR + 3) / 4, 256, 0, stream>>>(esorted, basep, X, comp1A, comp3A,
                                                Mix1blk, Mix3blk, n0, CR);
    int nx = nx_for(CR, 256);
    gemm_ms<<<2 * nx, 256, 0, stream>>>(
        Mix1blk, 2048, X + (size_t)n0 * 256, 256, nul, 0,
        2048, 2304, B1t, b1A, hA + (size_t)n0 * 256, 256, CR, 2304, 0, 256, nx,
        Mix3blk, X + (size_t)n0 * 256, B3t, b3A, hA3 + (size_t)n0 * 256);
  }
  // phase 2 — merged gconv aggregation (both convs) + dual gconv GEMM
  int nxN = nx_for(N, 256);
  gconv_agg2<<<nb4, 256, 0, stream>>>(esorted, basep, hA, hA3, AggA, AggC, N);
  cvt4<<<(N * 64 + 255) / 256, 256, 0, stream>>>(enc, X, N * 256, flag);  // X dead -> bf16 enc
  gemm_ms<<<2 * nxN, 256, 0, stream>>>(
      AggA, 256, hA, 256, nul, 0, 256, 512,
      B2t, b2A, hB, 256, N, 512, 0, 256, nxN,
      AggC, hA3, B4t, b4A, hC);

  // MLP layer 1: [enc|h1|h2] @ wd1 (+bd1, relu) -> h1m [N,128]
  int nx1 = nx_for(N, 128);
  gemm_ms<<<nx1, 256, 0, stream>>>(
      X, 256, hB, 256, hC, 256, 256, 512,
      D1t, bd1A, h1m, 128, N, 768, 1, 128, nx1,
      nul, nul, nul, nul, (u16*)nullptr);
  // MLP layer 2: h1m @ wd2 (+bd2, relu) -> h2m [N,64]
  int nx2 = nx_for(N, 64);
  gemm_ms<<<nx2, 256, 0, stream>>>(
      h1m, 128, nul, 0, nul, 0, 128, 128,
      wd2T, bd2A, h2m, 64, N, 128, 1, 64, nx2,
      nul, nul, nul, nul, (u16*)nullptr);
  // MLP layer 3
  mlp_tail2<<<nb4, 256, 0, stream>>>(h2m, wd3A, bd3A, d_out, N, flag);
}